// Round 14
// baseline (173.009 us; speedup 1.0000x reference)
//
#include <hip/hip_runtime.h>
#include <math.h>

#define D_MODEL 1024
#define D_INNER 2048
#define D_STATE 16
#define D_CONV  4
#define DT_RANK 64
#define BB      2
#define LL      1024
#define BL      (BB*LL)   // 2048 rows (B*L)
#define CHUNK   16
#define NCHUNK  (LL/CHUNK)   // 64
#define KSPLIT  16           // split-K for x_dbl GEMM
#define KS_E    (D_INNER/KSPLIT)   // 128 e-cols per split

typedef __attribute__((ext_vector_type(8))) short short8;
typedef __attribute__((ext_vector_type(4))) float f32x4;
typedef unsigned short ushort_t;
typedef unsigned int uint_t;

__device__ __forceinline__ float sigmoidf_(float x) { return 1.0f / (1.0f + __expf(-x)); }

__device__ __forceinline__ ushort_t f2bf(float f) {
    uint_t u = __float_as_uint(f);
    uint_t r = (u + 0x7fffu + ((u >> 16) & 1u)) >> 16;
    return (ushort_t)r;
}
__device__ __forceinline__ float bf2f(ushort_t v) {
    return __uint_as_float((uint_t)v << 16);
}

__device__ __forceinline__ void gload_lds16(const void* g, void* l) {
    __builtin_amdgcn_global_load_lds(
        (const __attribute__((address_space(1))) void*)g,
        (__attribute__((address_space(3))) void*)l,
        16, 0, 0);
}

// ---------------------------------------------------------------------------
// bf16 MFMA GEMM, templated tile: C = A[M,K] @ Bt[N,K]^T.
// 4 waves as 2(M) x 2(N); BK in {32,64}; 16x16x32 MFMA. 1D grid, XCD-swizzled.
// SPLIT: col-split epilogue. BF0/BF1: outputs bf16. KSPL>1: split-K partials
// to C0v + kz*M*N (fp32). MINW: blocks/CU target.
// BK=64 halves barrier count (2 MFMA sub-rounds per stage) -- R13 lever.
// gload_lds lane mapping: BK=32 -> 4 lanes/row (64B rows); BK=64 -> 8
// lanes/row (128B rows). Both keep LDS dest linear (wave-uniform base+lane*16).
// ---------------------------------------------------------------------------
template<int BM, int BN, int SPLIT, int BF0, int BF1, int KSPL, int MINW, int BK>
__global__ __launch_bounds__(256, MINW)
void gemm_bf16_t(const ushort_t* __restrict__ A, const ushort_t* __restrict__ Bt,
                 void* __restrict__ C0v, void* __restrict__ C1v,
                 int M, int N, int K, int split) {
    constexpr int WMr = BM / 32;
    constexpr int WNr = BN / 32;
    constexpr int KSUB = BK / 32;
    const int nx = N / BN;
    const int per = nx * (M / BM);
    const int nwg = per * KSPL;
    const int wg = ((blockIdx.x & 7) * (nwg >> 3)) + (blockIdx.x >> 3);
    const int kz = (KSPL > 1) ? (wg / per) : 0;
    const int rem = (KSPL > 1) ? (wg % per) : wg;
    const int row0 = (rem / nx) * BM;
    const int col0 = (rem % nx) * BN;
    const int Kh = K / KSPL;
    const int koff = kz * Kh;

    __shared__ __align__(16) ushort_t As[BM * BK];
    __shared__ __align__(16) ushort_t Bs[BN * BK];

    const int tid  = threadIdx.x;
    const int lane = tid & 63;
    const int wave = tid >> 6;
    const int wr = wave >> 1, wc = wave & 1;

    f32x4 acc[WMr][WNr];
    #pragma unroll
    for (int m = 0; m < WMr; ++m)
        #pragma unroll
        for (int n = 0; n < WNr; ++n)
            acc[m][n] = (f32x4){0.f, 0.f, 0.f, 0.f};

    const ushort_t* Ablk = A  + (size_t)row0 * K + koff;
    const ushort_t* Bblk = Bt + (size_t)col0 * K + koff;

    for (int k0 = 0; k0 < Kh; k0 += BK) {
        if (BK == 32) {
            const int r_ld  = tid >> 2;
            const int c8_ld = (tid & 3) * 8;
            #pragma unroll
            for (int i = 0; i < BM / 64; ++i)
                gload_lds16(Ablk + (size_t)(i * 64 + r_ld) * K + k0 + c8_ld,
                            &As[(i * 64 + wave * 16) * 32]);
            #pragma unroll
            for (int i = 0; i < BN / 64; ++i)
                gload_lds16(Bblk + (size_t)(i * 64 + r_ld) * K + k0 + c8_ld,
                            &Bs[(i * 64 + wave * 16) * 32]);
        } else {   // BK == 64: 8 lanes/row, 32 rows per instruction
            const int r_ld  = tid >> 3;
            const int c8_ld = (tid & 7) * 8;
            #pragma unroll
            for (int i = 0; i < BM / 32; ++i)
                gload_lds16(Ablk + (size_t)(i * 32 + r_ld) * K + k0 + c8_ld,
                            &As[(i * 32 + wave * 8) * 64]);
            #pragma unroll
            for (int i = 0; i < BN / 32; ++i)
                gload_lds16(Bblk + (size_t)(i * 32 + r_ld) * K + k0 + c8_ld,
                            &Bs[(i * 32 + wave * 8) * 64]);
        }
        __syncthreads();

        short8 af[WMr][KSUB], bf[WNr][KSUB];
        const int fr = lane & 15;
        const int kb = (lane >> 4) * 8;
        #pragma unroll
        for (int m = 0; m < WMr; ++m)
            #pragma unroll
            for (int ks = 0; ks < KSUB; ++ks)
                af[m][ks] = *(const short8*)
                    &As[(wr * WMr * 16 + m * 16 + fr) * BK + ks * 32 + kb];
        #pragma unroll
        for (int n = 0; n < WNr; ++n)
            #pragma unroll
            for (int ks = 0; ks < KSUB; ++ks)
                bf[n][ks] = *(const short8*)
                    &Bs[(wc * WNr * 16 + n * 16 + fr) * BK + ks * 32 + kb];

        #pragma unroll
        for (int ks = 0; ks < KSUB; ++ks)
            #pragma unroll
            for (int m = 0; m < WMr; ++m)
                #pragma unroll
                for (int n = 0; n < WNr; ++n)
                    acc[m][n] = __builtin_amdgcn_mfma_f32_16x16x32_bf16(
                        af[m][ks], bf[n][ks], acc[m][n], 0, 0, 0);
        __syncthreads();
    }

    const int crow = (lane >> 4) * 4;
    const int ccol = lane & 15;

    if (KSPL > 1) {
        float* Cb = (float*)C0v + (size_t)kz * M * N;
        #pragma unroll
        for (int m = 0; m < WMr; ++m) {
            #pragma unroll
            for (int n = 0; n < WNr; ++n) {
                float* cp = Cb + (size_t)(row0 + wr * WMr * 16 + m * 16 + crow) * N
                               + col0 + wc * WNr * 16 + n * 16 + ccol;
                #pragma unroll
                for (int i = 0; i < 4; ++i)
                    cp[(size_t)i * N] = acc[m][n][i];
            }
        }
        return;
    }

    const bool second = SPLIT && (col0 >= split);
    const int ldc = second ? (N - split) : (SPLIT ? split : N);
    const int cb  = second ? (col0 - split) : col0;

    #pragma unroll
    for (int m = 0; m < WMr; ++m) {
        #pragma unroll
        for (int n = 0; n < WNr; ++n) {
            size_t base = (size_t)(row0 + wr * WMr * 16 + m * 16 + crow) * ldc
                          + cb + wc * WNr * 16 + n * 16 + ccol;
            if (second) {
                if (BF1) { ushort_t* cp = (ushort_t*)C1v + base;
                    #pragma unroll
                    for (int i = 0; i < 4; ++i) cp[(size_t)i * ldc] = f2bf(acc[m][n][i]);
                } else { float* cp = (float*)C1v + base;
                    #pragma unroll
                    for (int i = 0; i < 4; ++i) cp[(size_t)i * ldc] = acc[m][n][i];
                }
            } else {
                if (BF0) { ushort_t* cp = (ushort_t*)C0v + base;
                    #pragma unroll
                    for (int i = 0; i < 4; ++i) cp[(size_t)i * ldc] = f2bf(acc[m][n][i]);
                } else { float* cp = (float*)C0v + base;
                    #pragma unroll
                    for (int i = 0; i < 4; ++i) cp[(size_t)i * ldc] = acc[m][n][i];
                }
            }
        }
    }
}

__global__ __launch_bounds__(256)
void out_reduce(const float* __restrict__ part, float* __restrict__ out, int n) {
    int i = (blockIdx.x * 256 + threadIdx.x) * 4;
    if (i + 4 <= n) {
        float4 a = *reinterpret_cast<const float4*>(part + i);
        float4 b = *reinterpret_cast<const float4*>(part + n + i);
        float4 r = {a.x + b.x, a.y + b.y, a.z + b.z, a.w + b.w};
        *reinterpret_cast<float4*>(out + i) = r;
    }
}

// ---------------------------------------------------------------------------
// Merged prep: job A (1024 blocks) x->bf16; job B (4096) W_in^T; job C (2048) W_out^T.
// ---------------------------------------------------------------------------
__device__ __forceinline__ void transp_tile_body(const float* __restrict__ W,
                                                 ushort_t* __restrict__ Wt,
                                                 int R, int C, int bx, int by,
                                                 ushort_t (*tile)[33]) {
    int tx = threadIdx.x & 31, ty = threadIdx.x >> 5;
    int r0 = by * 32, c0 = bx * 32;
    #pragma unroll
    for (int i = 0; i < 32; i += 8)
        tile[ty + i][tx] = f2bf(W[(size_t)(r0 + ty + i) * C + c0 + tx]);
    __syncthreads();
    #pragma unroll
    for (int i = 0; i < 32; i += 8)
        Wt[(size_t)(c0 + ty + i) * R + r0 + tx] = tile[tx][ty + i];
}

__global__ __launch_bounds__(256)
void prep_kernel(const float* __restrict__ x, ushort_t* __restrict__ x_bf,
                 const float* __restrict__ W_in, ushort_t* __restrict__ Wint,
                 const float* __restrict__ W_out, ushort_t* __restrict__ Woutt) {
    __shared__ ushort_t tile[32][33];
    int bid = blockIdx.x;
    if (bid < 1024) {
        int i = (bid * 256 + threadIdx.x) * 8;
        float4 a = *reinterpret_cast<const float4*>(x + i);
        float4 b = *reinterpret_cast<const float4*>(x + i + 4);
        ushort_t o[8] = {f2bf(a.x), f2bf(a.y), f2bf(a.z), f2bf(a.w),
                         f2bf(b.x), f2bf(b.y), f2bf(b.z), f2bf(b.w)};
        *reinterpret_cast<short8*>(x_bf + i) = *reinterpret_cast<short8*>(o);
    } else if (bid < 1024 + 4096) {
        int bi = bid - 1024;
        transp_tile_body(W_in, Wint, 1024, 4096, bi & 127, bi >> 7, tile);
    } else {
        int bi = bid - 5120;
        transp_tile_body(W_out, Woutt, 2048, 1024, bi & 31, bi >> 5, tile);
    }
}

// ---------------------------------------------------------------------------
// Split-K GEMM for x_dbl with FUSED depthwise conv + SiLU (xp in bf16):
// ---------------------------------------------------------------------------
__global__ __launch_bounds__(256)
void gemm_xdbl_convfused(const ushort_t* __restrict__ xp, const float* __restrict__ W,
                         const float* __restrict__ conv_w, const float* __restrict__ conv_b,
                         float* __restrict__ part) {
    __shared__ float Ax[16][68];
    __shared__ float Au[16][65];
    __shared__ float Bs[16][96];

    const int tid = threadIdx.x;
    const int m0 = blockIdx.x * 64;
    const int kbase = blockIdx.y * KS_E;
    const int tx = tid & 15;
    const int ty = tid >> 4;
    const bool bhead = (m0 & (LL - 1)) == 0;

    float acc[4][6] = {};

    for (int k0 = 0; k0 < KS_E; k0 += 16) {
        for (int i = tid; i < 67 * 16; i += 256) {
            int r = i >> 4, k = i & 15;
            float v = 0.f;
            if (!(bhead && r < 3))
                v = bf2f(xp[(size_t)(m0 - 3 + r) * D_INNER + kbase + k0 + k]);
            Ax[k][r] = v;
        }
        #pragma unroll
        for (int j = 0; j < 6; ++j) {
            int idx = j * 256 + tid;
            int row = idx / 96, col = idx - row * 96;
            Bs[row][col] = W[(size_t)(kbase + k0 + row) * 96 + col];
        }
        __syncthreads();
        {
            float4 w4 = *(const float4*)&conv_w[(size_t)(kbase + k0 + tx) * 4];
            float cbv = conv_b[kbase + k0 + tx];
            #pragma unroll
            for (int rr = 0; rr < 4; ++rr) {
                int r = ty + rr * 16;
                float a = cbv;
                a = fmaf(w4.x, Ax[tx][r], a);
                a = fmaf(w4.y, Ax[tx][r + 1], a);
                a = fmaf(w4.z, Ax[tx][r + 2], a);
                a = fmaf(w4.w, Ax[tx][r + 3], a);
                Au[tx][r] = a * sigmoidf_(a);
            }
        }
        __syncthreads();
        #pragma unroll
        for (int kk = 0; kk < 16; ++kk) {
            float a[4], b[6];
            #pragma unroll
            for (int i = 0; i < 4; ++i) a[i] = Au[kk][ty * 4 + i];
            #pragma unroll
            for (int j = 0; j < 6; ++j) b[j] = Bs[kk][tx * 6 + j];
            #pragma unroll
            for (int i = 0; i < 4; ++i)
                #pragma unroll
                for (int j = 0; j < 6; ++j)
                    acc[i][j] = fmaf(a[i], b[j], acc[i][j]);
        }
        __syncthreads();
    }

    float* pblk = part + (size_t)blockIdx.y * BL * 96;
    #pragma unroll
    for (int i = 0; i < 4; ++i)
        #pragma unroll
        for (int j = 0; j < 6; ++j)
            pblk[(size_t)(m0 + ty * 4 + i) * 96 + tx * 6 + j] = acc[i][j];
}

__global__ __launch_bounds__(256)
void xdbl_reduce(const float* __restrict__ part, float* __restrict__ x_dbl) {
    int i = blockIdx.x * 256 + threadIdx.x;
    float s = 0.0f;
    #pragma unroll
    for (int k = 0; k < KSPLIT; ++k)
        s += part[(size_t)k * BL * 96 + i];
    x_dbl[i] = s;
}

// ---------------------------------------------------------------------------
// Delta GEMM: delta(bf16) = softplus(x_dbl[:, :64] @ W_dt + dt_bias).
// Tile 64x64, K=64 (4 k-iters). Output bf16 halves write+scan-read traffic.
// ---------------------------------------------------------------------------
__global__ __launch_bounds__(256)
void gemm_delta(const float* __restrict__ A, const float* __restrict__ B,
                ushort_t* __restrict__ C, const float* __restrict__ bias,
                int M, int N, int K, int lda, int ldb, int ldc) {
    __shared__ float As[16][65];
    __shared__ float Bs[16][64];

    const int tid = threadIdx.x;
    const int tx = tid & 15;
    const int ty = tid >> 4;
    const int row0 = blockIdx.y * 64;
    const int col0 = blockIdx.x * 64;

    const int arow = tid >> 4;
    const int acol = tid & 15;
    const int brow = tid >> 6;
    const int bcol = tid & 63;

    float acc[4][4] = {};

    for (int k0 = 0; k0 < K; k0 += 16) {
        #pragma unroll
        for (int p = 0; p < 4; ++p) {
            int r = arow + p * 16;
            As[acol][r] = A[(size_t)(row0 + r) * lda + (k0 + acol)];
        }
        int gc = col0 + bcol;
        #pragma unroll
        for (int p = 0; p < 4; ++p) {
            int r = brow + p * 4;
            Bs[r][bcol] = B[(size_t)(k0 + r) * ldb + gc];
        }
        __syncthreads();
        #pragma unroll
        for (int kk = 0; kk < 16; ++kk) {
            float a[4];
            #pragma unroll
            for (int i = 0; i < 4; ++i) a[i] = As[kk][ty * 4 + i];
            float4 bv = *reinterpret_cast<const float4*>(&Bs[kk][tx * 4]);
            float b4[4] = {bv.x, bv.y, bv.z, bv.w};
            #pragma unroll
            for (int i = 0; i < 4; ++i)
                #pragma unroll
                for (int j = 0; j < 4; ++j)
                    acc[i][j] = fmaf(a[i], b4[j], acc[i][j]);
        }
        __syncthreads();
    }

    #pragma unroll
    for (int i = 0; i < 4; ++i) {
        int gr = row0 + ty * 4 + i;
        #pragma unroll
        for (int j = 0; j < 4; ++j) {
            int gc = col0 + tx * 4 + j;
            float v = acc[i][j] + bias[gc];
            v = (v > 20.0f) ? v : log1pf(__expf(v));
            C[(size_t)gr * ldc + gc] = f2bf(v);
        }
    }
}

// ---------------------------------------------------------------------------
// Chunked selective scan (delta/xp/hend bf16, conv fused, geo fast path).
// g = [b:1][c:6][e:11]. hend layout: [c][b][n][e]. sumdelta: [c][b][e].
// ---------------------------------------------------------------------------
__global__ __launch_bounds__(256)
void scan_phase1(const ushort_t* __restrict__ delta, const ushort_t* __restrict__ xp,
                 const float* __restrict__ conv_w, const float* __restrict__ conv_b,
                 const float* __restrict__ x_dbl, const float* __restrict__ A_log,
                 ushort_t* __restrict__ hend, float* __restrict__ sumdelta) {
    int g = blockIdx.x * 256 + threadIdx.x;
    int e = g & (D_INNER - 1);
    int c = (g >> 11) & (NCHUNK - 1);
    int b = g >> 17;

    float A_en[D_STATE];
    bool geo = true;
    #pragma unroll
    for (int n = 0; n < D_STATE; n += 4) {
        float4 al = *(const float4*)&A_log[e * D_STATE + n];
        A_en[n]     = -__expf(al.x);
        A_en[n + 1] = -__expf(al.y);
        A_en[n + 2] = -__expf(al.z);
        A_en[n + 3] = -__expf(al.w);
    }
    #pragma unroll
    for (int n = 0; n < D_STATE; ++n)
        geo = geo && (fabsf(A_en[n] + (float)(n + 1)) <= 2e-5f * (float)(n + 1));

    const int t0 = c * CHUNK;
    const ushort_t* dptr = delta + (size_t)(b * LL + t0) * D_INNER + e;
    const ushort_t* xptr = xp + (size_t)(b * LL + t0) * D_INNER + e;
    const float* xb   = x_dbl + (size_t)(b * LL + t0) * 96 + DT_RANK;
    float4 w4 = *(const float4*)&conv_w[(size_t)e * 4];
    float cbv = conv_b[e];

    float xw0 = 0.f, xw1 = 0.f, xw2 = 0.f;
    if (c > 0) {
        xw0 = bf2f(xptr[-3 * D_INNER]);
        xw1 = bf2f(xptr[-2 * D_INNER]);
        xw2 = bf2f(xptr[-1 * D_INNER]);
    }

    float h[D_STATE];
    #pragma unroll
    for (int n = 0; n < D_STATE; ++n) h[n] = 0.0f;
    float S = 0.0f;

    if (geo) {
        for (int t = 0; t < CHUNK; ++t) {
            float dv = bf2f(dptr[(size_t)t * D_INNER]);
            float x0 = bf2f(xptr[(size_t)t * D_INNER]);
            float a = cbv;
            a = fmaf(w4.x, xw0, a); a = fmaf(w4.y, xw1, a);
            a = fmaf(w4.z, xw2, a); a = fmaf(w4.w, x0, a);
            float uv = a * sigmoidf_(a);
            xw0 = xw1; xw1 = xw2; xw2 = x0;
            const float* xrow = xb + (size_t)t * 96;
            float4 B0 = *(const float4*)(xrow);
            float4 B1 = *(const float4*)(xrow + 4);
            float4 B2 = *(const float4*)(xrow + 8);
            float4 B3 = *(const float4*)(xrow + 12);
            float Bv[16] = {B0.x, B0.y, B0.z, B0.w, B1.x, B1.y, B1.z, B1.w,
                            B2.x, B2.y, B2.z, B2.w, B3.x, B3.y, B3.z, B3.w};
            S += dv;
            float du = dv * uv;
            float q = __expf(-dv);
            float dA = q;
            #pragma unroll
            for (int n = 0; n < D_STATE; ++n) {
                h[n] = fmaf(dA, h[n], du * Bv[n]);
                dA *= q;
            }
        }
    } else {
        for (int t = 0; t < CHUNK; ++t) {
            float dv = bf2f(dptr[(size_t)t * D_INNER]);
            float x0 = bf2f(xptr[(size_t)t * D_INNER]);
            float a = cbv;
            a = fmaf(w4.x, xw0, a); a = fmaf(w4.y, xw1, a);
            a = fmaf(w4.z, xw2, a); a = fmaf(w4.w, x0, a);
            float uv = a * sigmoidf_(a);
            xw0 = xw1; xw1 = xw2; xw2 = x0;
            const float* xrow = xb + (size_t)t * 96;
            float4 B0 = *(const float4*)(xrow);
            float4 B1 = *(const float4*)(xrow + 4);
            float4 B2 = *(const float4*)(xrow + 8);
            float4 B3 = *(const float4*)(xrow + 12);
            float Bv[16] = {B0.x, B0.y, B0.z, B0.w, B1.x, B1.y, B1.z, B1.w,
                            B2.x, B2.y, B2.z, B2.w, B3.x, B3.y, B3.z, B3.w};
            S += dv;
            float du = dv * uv;
            #pragma unroll
            for (int n = 0; n < D_STATE; ++n) {
                float dA = __expf(dv * A_en[n]);
                h[n] = fmaf(dA, h[n], du * Bv[n]);
            }
        }
    }

    size_t rbase = ((size_t)(c * BB + b) * D_STATE) * D_INNER + e;
    #pragma unroll
    for (int n = 0; n < D_STATE; ++n)
        hend[rbase + (size_t)n * D_INNER] = f2bf(h[n]);
    sumdelta[(size_t)(c * BB + b) * D_INNER + e] = S;
}

// In-place: hh holds hend(bf16) on entry, hin(bf16) on exit.
// 4x unrolled: 8 independent loads + 4 exps issue ahead of the 4-fma chain.
__global__ __launch_bounds__(256)
void scan_phase2(const float* __restrict__ A_log, const float* __restrict__ sumdelta,
                 ushort_t* __restrict__ hh) {
    int g = blockIdx.x * 256 + threadIdx.x;
    int e = g & (D_INNER - 1);
    int n = (g >> 11) & (D_STATE - 1);
    int b = g >> 15;
    float A_en = -__expf(A_log[e * D_STATE + n]);
    float np1 = (float)(n + 1);
    if (fabsf(A_en + np1) <= 2e-5f * np1) A_en = -np1;

    const size_t CS = (size_t)BB * D_STATE * D_INNER;   // hh stride per chunk
    const size_t DS = (size_t)BB * D_INNER;             // sumd stride per chunk
    size_t hidx = ((size_t)b * D_STATE + n) * D_INNER + e;
    size_t didx = (size_t)b * D_INNER + e;

    float h = 0.0f;
    #pragma unroll 1
    for (int c = 0; c < NCHUNK; c += 4) {
        float he0 = bf2f(hh[hidx]);
        float he1 = bf2f(hh[hidx + CS]);
        float he2 = bf2f(hh[hidx + 2 * CS]);
        float he3 = bf2f(hh[hidx + 3 * CS]);
        float q0 = __expf(A_en * sumdelta[didx]);
        float q1 = __expf(A_en * sumdelta[didx + DS]);
        float q2 = __expf(A_en * sumdelta[didx + 2 * DS]);
        float q3 = __expf(A_en * sumdelta[didx + 3 * DS]);
        hh[hidx] = f2bf(h);          h = fmaf(q0, h, he0);
        hh[hidx + CS] = f2bf(h);     h = fmaf(q1, h, he1);
        hh[hidx + 2 * CS] = f2bf(h); h = fmaf(q2, h, he2);
        hh[hidx + 3 * CS] = f2bf(h); h = fmaf(q3, h, he3);
        hidx += 4 * CS;
        didx += 4 * DS;
    }
}

__global__ __launch_bounds__(256)
void scan_phase3(const ushort_t* __restrict__ delta, const ushort_t* __restrict__ xp,
                 const float* __restrict__ conv_w, const float* __restrict__ conv_b,
                 const float* __restrict__ x_dbl, const ushort_t* __restrict__ zbf,
                 const float* __restrict__ A_log, const float* __restrict__ D_skip,
                 const ushort_t* __restrict__ hin, ushort_t* __restrict__ ybf) {
    int g = blockIdx.x * 256 + threadIdx.x;
    int e = g & (D_INNER - 1);
    int c = (g >> 11) & (NCHUNK - 1);
    int b = g >> 17;

    float A_en[D_STATE];
    bool geo = true;
    #pragma unroll
    for (int n = 0; n < D_STATE; n += 4) {
        float4 al = *(const float4*)&A_log[e * D_STATE + n];
        A_en[n]     = -__expf(al.x);
        A_en[n + 1] = -__expf(al.y);
        A_en[n + 2] = -__expf(al.z);
        A_en[n + 3] = -__expf(al.w);
    }
    #pragma unroll
    for (int n = 0; n < D_STATE; ++n)
        geo = geo && (fabsf(A_en[n] + (float)(n + 1)) <= 2e-5f * (float)(n + 1));

    float D_e = D_skip[e];
    float h[D_STATE];
    size_t rbase = ((size_t)(c * BB + b) * D_STATE) * D_INNER + e;
    #pragma unroll
    for (int n = 0; n < D_STATE; ++n)
        h[n] = bf2f(hin[rbase + (size_t)n * D_INNER]);

    const int t0 = c * CHUNK;
    const ushort_t* dptr = delta + (size_t)(b * LL + t0) * D_INNER + e;
    const ushort_t* xptr = xp + (size_t)(b * LL + t0) * D_INNER + e;
    const float* xb   = x_dbl + (size_t)(b * LL + t0) * 96 + DT_RANK;
    const ushort_t* zptr = zbf + (size_t)(b * LL + t0) * D_INNER + e;
    ushort_t* yout = ybf + (size_t)(b * LL + t0) * D_INNER + e;
    float4 w4 = *(const float4*)&conv_w[(size_t)e * 4];
    float cbv = conv_b[e];

    float xw0 = 0.f, xw1 = 0.f, xw2 = 0.f;
    if (c > 0) {
        xw0 = bf2f(xptr[-3 * D_INNER]);
        xw1 = bf2f(xptr[-2 * D_INNER]);
        xw2 = bf2f(xptr[-1 * D_INNER]);
    }

    if (geo) {
        for (int t = 0; t < CHUNK; ++t) {
            float dv = bf2f(dptr[(size_t)t * D_INNER]);
            float x0 = bf2f(xptr[(size_t)t * D_INNER]);
            float a = cbv;
            a = fmaf(w4.x, xw0, a); a = fmaf(w4.y, xw1, a);
            a = fmaf(w4.z, xw2, a); a = fmaf(w4.w, x0, a);
            float uv = a * sigmoidf_(a);
            xw0 = xw1; xw1 = xw2; xw2 = x0;
            const float* xrow = xb + (size_t)t * 96;
            float4 B0 = *(const float4*)(xrow);
            float4 B1 = *(const float4*)(xrow + 4);
            float4 B2 = *(const float4*)(xrow + 8);
            float4 B3 = *(const float4*)(xrow + 12);
            float4 C0 = *(const float4*)(xrow + 16);
            float4 C1 = *(const float4*)(xrow + 20);
            float4 C2 = *(const float4*)(xrow + 24);
            float4 C3 = *(const float4*)(xrow + 28);
            float Bv[16] = {B0.x, B0.y, B0.z, B0.w, B1.x, B1.y, B1.z, B1.w,
                            B2.x, B2.y, B2.z, B2.w, B3.x, B3.y, B3.z, B3.w};
            float Cv[16] = {C0.x, C0.y, C0.z, C0.w, C1.x, C1.y, C1.z, C1.w,
                            C2.x, C2.y, C2.z, C2.w, C3.x, C3.y, C3.z, C3.w};
            float du = dv * uv;
            float q = __expf(-dv);
            float dA = q;
            float y = 0.0f;
            #pragma unroll
            for (int n = 0; n < D_STATE; ++n) {
                h[n] = fmaf(dA, h[n], du * Bv[n]);
                y = fmaf(h[n], Cv[n], y);
                dA *= q;
            }
            float zv = bf2f(zptr[(size_t)t * D_INNER]);
            float yg = (y + uv * D_e) * (zv * sigmoidf_(zv));
            yout[(size_t)t * D_INNER] = f2bf(yg);
        }
    } else {
        for (int t = 0; t < CHUNK; ++t) {
            float dv = bf2f(dptr[(size_t)t * D_INNER]);
            float x0 = bf2f(xptr[(size_t)t * D_INNER]);
            float a = cbv;
            a = fmaf(w4.x, xw0, a); a = fmaf(w4.y, xw1, a);
            a = fmaf(w4.z, xw2, a); a = fmaf(w4.w, x0, a);
            float uv = a * sigmoidf_(a);
            xw0 = xw1; xw1 = xw2; xw2 = x0;
            const float* xrow = xb + (size_t)t * 96;
            float4 B0 = *(const float4*)(xrow);
            float4 B1 = *(const float4*)(xrow + 4);
            float4 B2 = *(const float4*)(xrow + 8);
            float4 B3 = *(const float4*)(xrow + 12);
            float4 C0 = *(const float4*)(xrow + 16);
            float4 C1 = *(const float4*)(xrow + 20);
            float4 C2 = *(const float4*)(xrow + 24);
            float4 C3 = *(const float4*)(xrow + 28);
            float Bv[16] = {B0.x, B0.y, B0.z, B0.w, B1.x, B1.y, B1.z, B1.w,
                            B2.x, B2.y, B2.z, B2.w, B3.x, B3.y, B3.z, B3.w};
            float Cv[16] = {C0.x, C0.y, C0.z, C0.w, C1.x, C1.y, C1.z, C1.w,
                            C2.x, C2.y, C2.z, C2.w, C3.x, C3.y, C3.z, C3.w};
            float du = dv * uv;
            float y = 0.0f;
            #pragma unroll
            for (int n = 0; n < D_STATE; ++n) {
                float dA = __expf(dv * A_en[n]);
                h[n] = fmaf(dA, h[n], du * Bv[n]);
                y = fmaf(h[n], Cv[n], y);
            }
            float zv = bf2f(zptr[(size_t)t * D_INNER]);
            float yg = (y + uv * D_e) * (zv * sigmoidf_(zv));
            yout[(size_t)t * D_INNER] = f2bf(yg);
        }
    }
}

// ---------------------------------------------------------------------------
extern "C" void kernel_launch(void* const* d_in, const int* in_sizes, int n_in,
                              void* d_out, int out_size, void* d_ws, size_t ws_size,
                              hipStream_t stream) {
    const float* x      = (const float*)d_in[0];
    const float* W_in   = (const float*)d_in[1];
    const float* conv_w = (const float*)d_in[2];
    const float* conv_b = (const float*)d_in[3];
    const float* W_xp   = (const float*)d_in[4];
    const float* W_dt   = (const float*)d_in[5];
    const float* dt_b   = (const float*)d_in[6];
    const float* A_log  = (const float*)d_in[7];
    const float* D_skip = (const float*)d_in[8];
    const float* W_out  = (const float*)d_in[9];
    float* out = (float*)d_out;

    // workspace ledger (float units). Peak = 18M floats = 72 MB (< proven 76.8).
    //   xp_bf  (bf16) [0, 2M)                step1 -> p3
    //   hend   (bf16) [4M, 6M)               p1 -> p3
    //   Wint_bf(bf16) [6M, 8M)               prep -> step1
    //   delta  (bf16) [8M, 9M)               step4 -> p3
    //     xdbl_part   [8M, 11M) (alias f32)  step2 -> step3  (pre-step4, ok)
    //     out_part    [8M, 12M) (alias f32)  step6 -> step7  (delta dead after p3)
    //   z_bf   (bf16) [12M, 14M)             step1 -> p3
    //   x_dbl  (f32)  [14M, +196608)         step3 -> p3
    //   sumd   (f32)  [14M+262144, +262144)  p1 -> p2
    //   ybf    (bf16) [14M+524288, 16M+524288) p3 -> step6
    //     x_bf (bf16) [14M+524288, 15M+524288) (alias) prep -> step1
    //   Woutt  (bf16) [17M, 18M)             prep -> step6
    const size_t M1 = 1024 * 1024;
    float* ws = (float*)d_ws;
    ushort_t* xp_bf = (ushort_t*)ws;
    ushort_t* hend  = (ushort_t*)(ws + 4 * M1);
    ushort_t* Wint_bf = (ushort_t*)(ws + 6 * M1);
    ushort_t* delta = (ushort_t*)(ws + 8 * M1);
    ushort_t* z_bf  = (ushort_t*)(ws + 12 * M1);
    float*    x_dbl = ws + 14 * M1;
    float*    sumd  = ws + 14 * M1 + 262144;
    ushort_t* ybf   = (ushort_t*)(ws + 14 * M1 + 524288);
    float*    xdbl_part = ws + 8 * M1;
    float*    out_part  = ws + 8 * M1;
    ushort_t* x_bf  = ybf;
    ushort_t* Woutt_bf = (ushort_t*)(ws + 17 * M1);

    dim3 blk(256);

    // 0) merged prep: x->bf16, W_in^T, W_out^T
    hipLaunchKernelGGL(prep_kernel, dim3(1024 + 4096 + 2048), blk, 0, stream,
                       x, x_bf, W_in, Wint_bf, W_out, Woutt_bf);
    // 1) [xp(bf16) | z(bf16)] = x @ W_in  (64x128 tile, BK=64, 1024 blocks)
    hipLaunchKernelGGL((gemm_bf16_t<64, 128, 1, 1, 1, 1, 4, 64>),
                       dim3((BL / 64) * (4096 / 128)), blk, 0, stream,
                       x_bf, Wint_bf, (void*)xp_bf, (void*)z_bf,
                       BL, 2 * D_INNER, D_MODEL, D_INNER);
    // 2) x_dbl partials = silu(conv(xp)) @ W_xp   (conv fused, split-K)
    hipLaunchKernelGGL(gemm_xdbl_convfused, dim3(BL / 64, KSPLIT), blk, 0, stream,
                       xp_bf, W_xp, conv_w, conv_b, xdbl_part);
    // 3) reduce partials -> x_dbl
    hipLaunchKernelGGL(xdbl_reduce, dim3((BL * 96) / 256), blk, 0, stream,
                       xdbl_part, x_dbl);
    // 4) delta(bf16) = softplus(x_dbl[:, :64] @ W_dt + dt_bias)
    hipLaunchKernelGGL(gemm_delta, dim3(D_INNER / 64, BL / 64), blk, 0, stream,
                       x_dbl, W_dt, delta, dt_b, BL, D_INNER, DT_RANK, 96, D_INNER, D_INNER);
    // 5) chunked selective scan -> ybf
    hipLaunchKernelGGL(scan_phase1, dim3((BB * NCHUNK * D_INNER) / 256), blk, 0, stream,
                       delta, xp_bf, conv_w, conv_b, x_dbl, A_log, hend, sumd);
    hipLaunchKernelGGL(scan_phase2, dim3((BB * D_STATE * D_INNER) / 256), blk, 0, stream,
                       A_log, sumd, hend);
    hipLaunchKernelGGL(scan_phase3, dim3((BB * NCHUNK * D_INNER) / 256), blk, 0, stream,
                       delta, xp_bf, conv_w, conv_b, x_dbl, z_bf, A_log, D_skip, hend, ybf);
    // 6) out partials = ybf @ W_out  (64x64 tile, BK=32, split-K=2)
    hipLaunchKernelGGL((gemm_bf16_t<64, 64, 0, 0, 0, 2, 8, 32>),
                       dim3((BL / 64) * (D_MODEL / 64) * 2), blk, 0, stream,
                       ybf, Woutt_bf, (void*)out_part, (void*)out_part,
                       BL, D_MODEL, D_INNER, D_MODEL);
    // 7) reduce the two K-halves -> out
    hipLaunchKernelGGL(out_reduce, dim3((BL * D_MODEL) / (256 * 4)), blk, 0, stream,
                       out_part, out, BL * D_MODEL);
}

// Round 15
// 171.412 us; speedup vs baseline: 1.0093x; 1.0093x over previous
//
#include <hip/hip_runtime.h>
#include <math.h>

#define D_MODEL 1024
#define D_INNER 2048
#define D_STATE 16
#define D_CONV  4
#define DT_RANK 64
#define BB      2
#define LL      1024
#define BL      (BB*LL)   // 2048 rows (B*L)
#define CHUNK   16
#define NCHUNK  (LL/CHUNK)   // 64
#define KSPLIT  16           // split-K for x_dbl GEMM
#define KS_E    (D_INNER/KSPLIT)   // 128 e-cols per split

typedef __attribute__((ext_vector_type(8))) short short8;
typedef __attribute__((ext_vector_type(4))) float f32x4;
typedef unsigned short ushort_t;
typedef unsigned int uint_t;

__device__ __forceinline__ float sigmoidf_(float x) { return 1.0f / (1.0f + __expf(-x)); }

__device__ __forceinline__ ushort_t f2bf(float f) {
    uint_t u = __float_as_uint(f);
    uint_t r = (u + 0x7fffu + ((u >> 16) & 1u)) >> 16;
    return (ushort_t)r;
}
__device__ __forceinline__ float bf2f(ushort_t v) {
    return __uint_as_float((uint_t)v << 16);
}

__device__ __forceinline__ void gload_lds16(const void* g, void* l) {
    __builtin_amdgcn_global_load_lds(
        (const __attribute__((address_space(1))) void*)g,
        (__attribute__((address_space(3))) void*)l,
        16, 0, 0);
}

// ---------------------------------------------------------------------------
// bf16 MFMA GEMM, templated tile: C = A[M,K] @ Bt[N,K]^T.
// 4 waves as 2(M) x 2(N); BK in {32,64}; 16x16x32 MFMA. 1D grid, XCD-swizzled.
// SPLIT: col-split epilogue. BF0/BF1: outputs bf16. KSPL>1: split-K partials
// to C0v + kz*M*N (fp32). MINW: blocks/CU target.
// R14 lesson: BK=64 is NOT a win here (VGPR pressure offsets barrier savings);
// BK=32 with 4 blocks/CU is the measured optimum for in_proj.
// ---------------------------------------------------------------------------
template<int BM, int BN, int SPLIT, int BF0, int BF1, int KSPL, int MINW, int BK>
__global__ __launch_bounds__(256, MINW)
void gemm_bf16_t(const ushort_t* __restrict__ A, const ushort_t* __restrict__ Bt,
                 void* __restrict__ C0v, void* __restrict__ C1v,
                 int M, int N, int K, int split) {
    constexpr int WMr = BM / 32;
    constexpr int WNr = BN / 32;
    constexpr int KSUB = BK / 32;
    const int nx = N / BN;
    const int per = nx * (M / BM);
    const int nwg = per * KSPL;
    const int wg = ((blockIdx.x & 7) * (nwg >> 3)) + (blockIdx.x >> 3);
    const int kz = (KSPL > 1) ? (wg / per) : 0;
    const int rem = (KSPL > 1) ? (wg % per) : wg;
    const int row0 = (rem / nx) * BM;
    const int col0 = (rem % nx) * BN;
    const int Kh = K / KSPL;
    const int koff = kz * Kh;

    __shared__ __align__(16) ushort_t As[BM * BK];
    __shared__ __align__(16) ushort_t Bs[BN * BK];

    const int tid  = threadIdx.x;
    const int lane = tid & 63;
    const int wave = tid >> 6;
    const int wr = wave >> 1, wc = wave & 1;

    f32x4 acc[WMr][WNr];
    #pragma unroll
    for (int m = 0; m < WMr; ++m)
        #pragma unroll
        for (int n = 0; n < WNr; ++n)
            acc[m][n] = (f32x4){0.f, 0.f, 0.f, 0.f};

    const ushort_t* Ablk = A  + (size_t)row0 * K + koff;
    const ushort_t* Bblk = Bt + (size_t)col0 * K + koff;

    for (int k0 = 0; k0 < Kh; k0 += BK) {
        if (BK == 32) {
            const int r_ld  = tid >> 2;
            const int c8_ld = (tid & 3) * 8;
            #pragma unroll
            for (int i = 0; i < BM / 64; ++i)
                gload_lds16(Ablk + (size_t)(i * 64 + r_ld) * K + k0 + c8_ld,
                            &As[(i * 64 + wave * 16) * 32]);
            #pragma unroll
            for (int i = 0; i < BN / 64; ++i)
                gload_lds16(Bblk + (size_t)(i * 64 + r_ld) * K + k0 + c8_ld,
                            &Bs[(i * 64 + wave * 16) * 32]);
        } else {   // BK == 64: 8 lanes/row, 32 rows per instruction
            const int r_ld  = tid >> 3;
            const int c8_ld = (tid & 7) * 8;
            #pragma unroll
            for (int i = 0; i < BM / 32; ++i)
                gload_lds16(Ablk + (size_t)(i * 32 + r_ld) * K + k0 + c8_ld,
                            &As[(i * 32 + wave * 8) * 64]);
            #pragma unroll
            for (int i = 0; i < BN / 32; ++i)
                gload_lds16(Bblk + (size_t)(i * 32 + r_ld) * K + k0 + c8_ld,
                            &Bs[(i * 32 + wave * 8) * 64]);
        }
        __syncthreads();

        short8 af[WMr][KSUB], bf[WNr][KSUB];
        const int fr = lane & 15;
        const int kb = (lane >> 4) * 8;
        #pragma unroll
        for (int m = 0; m < WMr; ++m)
            #pragma unroll
            for (int ks = 0; ks < KSUB; ++ks)
                af[m][ks] = *(const short8*)
                    &As[(wr * WMr * 16 + m * 16 + fr) * BK + ks * 32 + kb];
        #pragma unroll
        for (int n = 0; n < WNr; ++n)
            #pragma unroll
            for (int ks = 0; ks < KSUB; ++ks)
                bf[n][ks] = *(const short8*)
                    &Bs[(wc * WNr * 16 + n * 16 + fr) * BK + ks * 32 + kb];

        #pragma unroll
        for (int ks = 0; ks < KSUB; ++ks)
            #pragma unroll
            for (int m = 0; m < WMr; ++m)
                #pragma unroll
                for (int n = 0; n < WNr; ++n)
                    acc[m][n] = __builtin_amdgcn_mfma_f32_16x16x32_bf16(
                        af[m][ks], bf[n][ks], acc[m][n], 0, 0, 0);
        __syncthreads();
    }

    const int crow = (lane >> 4) * 4;
    const int ccol = lane & 15;

    if (KSPL > 1) {
        float* Cb = (float*)C0v + (size_t)kz * M * N;
        #pragma unroll
        for (int m = 0; m < WMr; ++m) {
            #pragma unroll
            for (int n = 0; n < WNr; ++n) {
                float* cp = Cb + (size_t)(row0 + wr * WMr * 16 + m * 16 + crow) * N
                               + col0 + wc * WNr * 16 + n * 16 + ccol;
                #pragma unroll
                for (int i = 0; i < 4; ++i)
                    cp[(size_t)i * N] = acc[m][n][i];
            }
        }
        return;
    }

    const bool second = SPLIT && (col0 >= split);
    const int ldc = second ? (N - split) : (SPLIT ? split : N);
    const int cb  = second ? (col0 - split) : col0;

    #pragma unroll
    for (int m = 0; m < WMr; ++m) {
        #pragma unroll
        for (int n = 0; n < WNr; ++n) {
            size_t base = (size_t)(row0 + wr * WMr * 16 + m * 16 + crow) * ldc
                          + cb + wc * WNr * 16 + n * 16 + ccol;
            if (second) {
                if (BF1) { ushort_t* cp = (ushort_t*)C1v + base;
                    #pragma unroll
                    for (int i = 0; i < 4; ++i) cp[(size_t)i * ldc] = f2bf(acc[m][n][i]);
                } else { float* cp = (float*)C1v + base;
                    #pragma unroll
                    for (int i = 0; i < 4; ++i) cp[(size_t)i * ldc] = acc[m][n][i];
                }
            } else {
                if (BF0) { ushort_t* cp = (ushort_t*)C0v + base;
                    #pragma unroll
                    for (int i = 0; i < 4; ++i) cp[(size_t)i * ldc] = f2bf(acc[m][n][i]);
                } else { float* cp = (float*)C0v + base;
                    #pragma unroll
                    for (int i = 0; i < 4; ++i) cp[(size_t)i * ldc] = acc[m][n][i];
                }
            }
        }
    }
}

__global__ __launch_bounds__(256)
void out_reduce(const float* __restrict__ part, float* __restrict__ out, int n) {
    int i = (blockIdx.x * 256 + threadIdx.x) * 4;
    if (i + 4 <= n) {
        float4 a = *reinterpret_cast<const float4*>(part + i);
        float4 b = *reinterpret_cast<const float4*>(part + n + i);
        float4 r = {a.x + b.x, a.y + b.y, a.z + b.z, a.w + b.w};
        *reinterpret_cast<float4*>(out + i) = r;
    }
}

// ---------------------------------------------------------------------------
// Merged prep: job A (1024 blocks) x->bf16; job B (4096) W_in^T; job C (2048) W_out^T.
// ---------------------------------------------------------------------------
__device__ __forceinline__ void transp_tile_body(const float* __restrict__ W,
                                                 ushort_t* __restrict__ Wt,
                                                 int R, int C, int bx, int by,
                                                 ushort_t (*tile)[33]) {
    int tx = threadIdx.x & 31, ty = threadIdx.x >> 5;
    int r0 = by * 32, c0 = bx * 32;
    #pragma unroll
    for (int i = 0; i < 32; i += 8)
        tile[ty + i][tx] = f2bf(W[(size_t)(r0 + ty + i) * C + c0 + tx]);
    __syncthreads();
    #pragma unroll
    for (int i = 0; i < 32; i += 8)
        Wt[(size_t)(c0 + ty + i) * R + r0 + tx] = tile[tx][ty + i];
}

__global__ __launch_bounds__(256)
void prep_kernel(const float* __restrict__ x, ushort_t* __restrict__ x_bf,
                 const float* __restrict__ W_in, ushort_t* __restrict__ Wint,
                 const float* __restrict__ W_out, ushort_t* __restrict__ Woutt) {
    __shared__ ushort_t tile[32][33];
    int bid = blockIdx.x;
    if (bid < 1024) {
        int i = (bid * 256 + threadIdx.x) * 8;
        float4 a = *reinterpret_cast<const float4*>(x + i);
        float4 b = *reinterpret_cast<const float4*>(x + i + 4);
        ushort_t o[8] = {f2bf(a.x), f2bf(a.y), f2bf(a.z), f2bf(a.w),
                         f2bf(b.x), f2bf(b.y), f2bf(b.z), f2bf(b.w)};
        *reinterpret_cast<short8*>(x_bf + i) = *reinterpret_cast<short8*>(o);
    } else if (bid < 1024 + 4096) {
        int bi = bid - 1024;
        transp_tile_body(W_in, Wint, 1024, 4096, bi & 127, bi >> 7, tile);
    } else {
        int bi = bid - 5120;
        transp_tile_body(W_out, Woutt, 2048, 1024, bi & 31, bi >> 5, tile);
    }
}

// ---------------------------------------------------------------------------
// Split-K GEMM for x_dbl with FUSED depthwise conv + SiLU (xp in bf16):
// ---------------------------------------------------------------------------
__global__ __launch_bounds__(256)
void gemm_xdbl_convfused(const ushort_t* __restrict__ xp, const float* __restrict__ W,
                         const float* __restrict__ conv_w, const float* __restrict__ conv_b,
                         float* __restrict__ part) {
    __shared__ float Ax[16][68];
    __shared__ float Au[16][65];
    __shared__ float Bs[16][96];

    const int tid = threadIdx.x;
    const int m0 = blockIdx.x * 64;
    const int kbase = blockIdx.y * KS_E;
    const int tx = tid & 15;
    const int ty = tid >> 4;
    const bool bhead = (m0 & (LL - 1)) == 0;

    float acc[4][6] = {};

    for (int k0 = 0; k0 < KS_E; k0 += 16) {
        for (int i = tid; i < 67 * 16; i += 256) {
            int r = i >> 4, k = i & 15;
            float v = 0.f;
            if (!(bhead && r < 3))
                v = bf2f(xp[(size_t)(m0 - 3 + r) * D_INNER + kbase + k0 + k]);
            Ax[k][r] = v;
        }
        #pragma unroll
        for (int j = 0; j < 6; ++j) {
            int idx = j * 256 + tid;
            int row = idx / 96, col = idx - row * 96;
            Bs[row][col] = W[(size_t)(kbase + k0 + row) * 96 + col];
        }
        __syncthreads();
        {
            float4 w4 = *(const float4*)&conv_w[(size_t)(kbase + k0 + tx) * 4];
            float cbv = conv_b[kbase + k0 + tx];
            #pragma unroll
            for (int rr = 0; rr < 4; ++rr) {
                int r = ty + rr * 16;
                float a = cbv;
                a = fmaf(w4.x, Ax[tx][r], a);
                a = fmaf(w4.y, Ax[tx][r + 1], a);
                a = fmaf(w4.z, Ax[tx][r + 2], a);
                a = fmaf(w4.w, Ax[tx][r + 3], a);
                Au[tx][r] = a * sigmoidf_(a);
            }
        }
        __syncthreads();
        #pragma unroll
        for (int kk = 0; kk < 16; ++kk) {
            float a[4], b[6];
            #pragma unroll
            for (int i = 0; i < 4; ++i) a[i] = Au[kk][ty * 4 + i];
            #pragma unroll
            for (int j = 0; j < 6; ++j) b[j] = Bs[kk][tx * 6 + j];
            #pragma unroll
            for (int i = 0; i < 4; ++i)
                #pragma unroll
                for (int j = 0; j < 6; ++j)
                    acc[i][j] = fmaf(a[i], b[j], acc[i][j]);
        }
        __syncthreads();
    }

    float* pblk = part + (size_t)blockIdx.y * BL * 96;
    #pragma unroll
    for (int i = 0; i < 4; ++i)
        #pragma unroll
        for (int j = 0; j < 6; ++j)
            pblk[(size_t)(m0 + ty * 4 + i) * 96 + tx * 6 + j] = acc[i][j];
}

__global__ __launch_bounds__(256)
void xdbl_reduce(const float* __restrict__ part, float* __restrict__ x_dbl) {
    int i = blockIdx.x * 256 + threadIdx.x;
    float s = 0.0f;
    #pragma unroll
    for (int k = 0; k < KSPLIT; ++k)
        s += part[(size_t)k * BL * 96 + i];
    x_dbl[i] = s;
}

// ---------------------------------------------------------------------------
// Delta GEMM: delta(bf16) = softplus(x_dbl[:, :64] @ W_dt + dt_bias).
// ---------------------------------------------------------------------------
__global__ __launch_bounds__(256)
void gemm_delta(const float* __restrict__ A, const float* __restrict__ B,
                ushort_t* __restrict__ C, const float* __restrict__ bias,
                int M, int N, int K, int lda, int ldb, int ldc) {
    __shared__ float As[16][65];
    __shared__ float Bs[16][64];

    const int tid = threadIdx.x;
    const int tx = tid & 15;
    const int ty = tid >> 4;
    const int row0 = blockIdx.y * 64;
    const int col0 = blockIdx.x * 64;

    const int arow = tid >> 4;
    const int acol = tid & 15;
    const int brow = tid >> 6;
    const int bcol = tid & 63;

    float acc[4][4] = {};

    for (int k0 = 0; k0 < K; k0 += 16) {
        #pragma unroll
        for (int p = 0; p < 4; ++p) {
            int r = arow + p * 16;
            As[acol][r] = A[(size_t)(row0 + r) * lda + (k0 + acol)];
        }
        int gc = col0 + bcol;
        #pragma unroll
        for (int p = 0; p < 4; ++p) {
            int r = brow + p * 4;
            Bs[r][bcol] = B[(size_t)(k0 + r) * ldb + gc];
        }
        __syncthreads();
        #pragma unroll
        for (int kk = 0; kk < 16; ++kk) {
            float a[4];
            #pragma unroll
            for (int i = 0; i < 4; ++i) a[i] = As[kk][ty * 4 + i];
            float4 bv = *reinterpret_cast<const float4*>(&Bs[kk][tx * 4]);
            float b4[4] = {bv.x, bv.y, bv.z, bv.w};
            #pragma unroll
            for (int i = 0; i < 4; ++i)
                #pragma unroll
                for (int j = 0; j < 4; ++j)
                    acc[i][j] = fmaf(a[i], b4[j], acc[i][j]);
        }
        __syncthreads();
    }

    #pragma unroll
    for (int i = 0; i < 4; ++i) {
        int gr = row0 + ty * 4 + i;
        #pragma unroll
        for (int j = 0; j < 4; ++j) {
            int gc = col0 + tx * 4 + j;
            float v = acc[i][j] + bias[gc];
            v = (v > 20.0f) ? v : log1pf(__expf(v));
            C[(size_t)gr * ldc + gc] = f2bf(v);
        }
    }
}

// ---------------------------------------------------------------------------
// Chunked selective scan (delta/xp/hend bf16, conv fused, geo fast path).
// g = [b:1][c:6][e:11]. hend layout: [c][b][n][e]. sumdelta: [c][b][e].
// ---------------------------------------------------------------------------
__global__ __launch_bounds__(256)
void scan_phase1(const ushort_t* __restrict__ delta, const ushort_t* __restrict__ xp,
                 const float* __restrict__ conv_w, const float* __restrict__ conv_b,
                 const float* __restrict__ x_dbl, const float* __restrict__ A_log,
                 ushort_t* __restrict__ hend, float* __restrict__ sumdelta) {
    int g = blockIdx.x * 256 + threadIdx.x;
    int e = g & (D_INNER - 1);
    int c = (g >> 11) & (NCHUNK - 1);
    int b = g >> 17;

    float A_en[D_STATE];
    bool geo = true;
    #pragma unroll
    for (int n = 0; n < D_STATE; n += 4) {
        float4 al = *(const float4*)&A_log[e * D_STATE + n];
        A_en[n]     = -__expf(al.x);
        A_en[n + 1] = -__expf(al.y);
        A_en[n + 2] = -__expf(al.z);
        A_en[n + 3] = -__expf(al.w);
    }
    #pragma unroll
    for (int n = 0; n < D_STATE; ++n)
        geo = geo && (fabsf(A_en[n] + (float)(n + 1)) <= 2e-5f * (float)(n + 1));

    const int t0 = c * CHUNK;
    const ushort_t* dptr = delta + (size_t)(b * LL + t0) * D_INNER + e;
    const ushort_t* xptr = xp + (size_t)(b * LL + t0) * D_INNER + e;
    const float* xb   = x_dbl + (size_t)(b * LL + t0) * 96 + DT_RANK;
    float4 w4 = *(const float4*)&conv_w[(size_t)e * 4];
    float cbv = conv_b[e];

    float xw0 = 0.f, xw1 = 0.f, xw2 = 0.f;
    if (c > 0) {
        xw0 = bf2f(xptr[-3 * D_INNER]);
        xw1 = bf2f(xptr[-2 * D_INNER]);
        xw2 = bf2f(xptr[-1 * D_INNER]);
    }

    float h[D_STATE];
    #pragma unroll
    for (int n = 0; n < D_STATE; ++n) h[n] = 0.0f;
    float S = 0.0f;

    if (geo) {
        #pragma unroll 2
        for (int t = 0; t < CHUNK; ++t) {
            float dv = bf2f(dptr[(size_t)t * D_INNER]);
            float x0 = bf2f(xptr[(size_t)t * D_INNER]);
            float a = cbv;
            a = fmaf(w4.x, xw0, a); a = fmaf(w4.y, xw1, a);
            a = fmaf(w4.z, xw2, a); a = fmaf(w4.w, x0, a);
            float uv = a * sigmoidf_(a);
            xw0 = xw1; xw1 = xw2; xw2 = x0;
            const float* xrow = xb + (size_t)t * 96;
            float4 B0 = *(const float4*)(xrow);
            float4 B1 = *(const float4*)(xrow + 4);
            float4 B2 = *(const float4*)(xrow + 8);
            float4 B3 = *(const float4*)(xrow + 12);
            float Bv[16] = {B0.x, B0.y, B0.z, B0.w, B1.x, B1.y, B1.z, B1.w,
                            B2.x, B2.y, B2.z, B2.w, B3.x, B3.y, B3.z, B3.w};
            S += dv;
            float du = dv * uv;
            float q = __expf(-dv);
            float dA = q;
            #pragma unroll
            for (int n = 0; n < D_STATE; ++n) {
                h[n] = fmaf(dA, h[n], du * Bv[n]);
                dA *= q;
            }
        }
    } else {
        for (int t = 0; t < CHUNK; ++t) {
            float dv = bf2f(dptr[(size_t)t * D_INNER]);
            float x0 = bf2f(xptr[(size_t)t * D_INNER]);
            float a = cbv;
            a = fmaf(w4.x, xw0, a); a = fmaf(w4.y, xw1, a);
            a = fmaf(w4.z, xw2, a); a = fmaf(w4.w, x0, a);
            float uv = a * sigmoidf_(a);
            xw0 = xw1; xw1 = xw2; xw2 = x0;
            const float* xrow = xb + (size_t)t * 96;
            float4 B0 = *(const float4*)(xrow);
            float4 B1 = *(const float4*)(xrow + 4);
            float4 B2 = *(const float4*)(xrow + 8);
            float4 B3 = *(const float4*)(xrow + 12);
            float Bv[16] = {B0.x, B0.y, B0.z, B0.w, B1.x, B1.y, B1.z, B1.w,
                            B2.x, B2.y, B2.z, B2.w, B3.x, B3.y, B3.z, B3.w};
            S += dv;
            float du = dv * uv;
            #pragma unroll
            for (int n = 0; n < D_STATE; ++n) {
                float dA = __expf(dv * A_en[n]);
                h[n] = fmaf(dA, h[n], du * Bv[n]);
            }
        }
    }

    size_t rbase = ((size_t)(c * BB + b) * D_STATE) * D_INNER + e;
    #pragma unroll
    for (int n = 0; n < D_STATE; ++n)
        hend[rbase + (size_t)n * D_INNER] = f2bf(h[n]);
    sumdelta[(size_t)(c * BB + b) * D_INNER + e] = S;
}

// In-place: hh holds hend(bf16) on entry, hin(bf16) on exit.
// 4x unrolled: 8 independent loads + 4 exps issue ahead of the 4-fma chain.
__global__ __launch_bounds__(256)
void scan_phase2(const float* __restrict__ A_log, const float* __restrict__ sumdelta,
                 ushort_t* __restrict__ hh) {
    int g = blockIdx.x * 256 + threadIdx.x;
    int e = g & (D_INNER - 1);
    int n = (g >> 11) & (D_STATE - 1);
    int b = g >> 15;
    float A_en = -__expf(A_log[e * D_STATE + n]);
    float np1 = (float)(n + 1);
    if (fabsf(A_en + np1) <= 2e-5f * np1) A_en = -np1;

    const size_t CS = (size_t)BB * D_STATE * D_INNER;   // hh stride per chunk
    const size_t DS = (size_t)BB * D_INNER;             // sumd stride per chunk
    size_t hidx = ((size_t)b * D_STATE + n) * D_INNER + e;
    size_t didx = (size_t)b * D_INNER + e;

    float h = 0.0f;
    #pragma unroll 1
    for (int c = 0; c < NCHUNK; c += 4) {
        float he0 = bf2f(hh[hidx]);
        float he1 = bf2f(hh[hidx + CS]);
        float he2 = bf2f(hh[hidx + 2 * CS]);
        float he3 = bf2f(hh[hidx + 3 * CS]);
        float q0 = __expf(A_en * sumdelta[didx]);
        float q1 = __expf(A_en * sumdelta[didx + DS]);
        float q2 = __expf(A_en * sumdelta[didx + 2 * DS]);
        float q3 = __expf(A_en * sumdelta[didx + 3 * DS]);
        hh[hidx] = f2bf(h);          h = fmaf(q0, h, he0);
        hh[hidx + CS] = f2bf(h);     h = fmaf(q1, h, he1);
        hh[hidx + 2 * CS] = f2bf(h); h = fmaf(q2, h, he2);
        hh[hidx + 3 * CS] = f2bf(h); h = fmaf(q3, h, he3);
        hidx += 4 * CS;
        didx += 4 * DS;
    }
}

__global__ __launch_bounds__(256)
void scan_phase3(const ushort_t* __restrict__ delta, const ushort_t* __restrict__ xp,
                 const float* __restrict__ conv_w, const float* __restrict__ conv_b,
                 const float* __restrict__ x_dbl, const ushort_t* __restrict__ zbf,
                 const float* __restrict__ A_log, const float* __restrict__ D_skip,
                 const ushort_t* __restrict__ hin, ushort_t* __restrict__ ybf) {
    int g = blockIdx.x * 256 + threadIdx.x;
    int e = g & (D_INNER - 1);
    int c = (g >> 11) & (NCHUNK - 1);
    int b = g >> 17;

    float A_en[D_STATE];
    bool geo = true;
    #pragma unroll
    for (int n = 0; n < D_STATE; n += 4) {
        float4 al = *(const float4*)&A_log[e * D_STATE + n];
        A_en[n]     = -__expf(al.x);
        A_en[n + 1] = -__expf(al.y);
        A_en[n + 2] = -__expf(al.z);
        A_en[n + 3] = -__expf(al.w);
    }
    #pragma unroll
    for (int n = 0; n < D_STATE; ++n)
        geo = geo && (fabsf(A_en[n] + (float)(n + 1)) <= 2e-5f * (float)(n + 1));

    float D_e = D_skip[e];
    float h[D_STATE];
    size_t rbase = ((size_t)(c * BB + b) * D_STATE) * D_INNER + e;
    #pragma unroll
    for (int n = 0; n < D_STATE; ++n)
        h[n] = bf2f(hin[rbase + (size_t)n * D_INNER]);

    const int t0 = c * CHUNK;
    const ushort_t* dptr = delta + (size_t)(b * LL + t0) * D_INNER + e;
    const ushort_t* xptr = xp + (size_t)(b * LL + t0) * D_INNER + e;
    const float* xb   = x_dbl + (size_t)(b * LL + t0) * 96 + DT_RANK;
    const ushort_t* zptr = zbf + (size_t)(b * LL + t0) * D_INNER + e;
    ushort_t* yout = ybf + (size_t)(b * LL + t0) * D_INNER + e;
    float4 w4 = *(const float4*)&conv_w[(size_t)e * 4];
    float cbv = conv_b[e];

    float xw0 = 0.f, xw1 = 0.f, xw2 = 0.f;
    if (c > 0) {
        xw0 = bf2f(xptr[-3 * D_INNER]);
        xw1 = bf2f(xptr[-2 * D_INNER]);
        xw2 = bf2f(xptr[-1 * D_INNER]);
    }

    if (geo) {
        #pragma unroll 2
        for (int t = 0; t < CHUNK; ++t) {
            float dv = bf2f(dptr[(size_t)t * D_INNER]);
            float x0 = bf2f(xptr[(size_t)t * D_INNER]);
            float a = cbv;
            a = fmaf(w4.x, xw0, a); a = fmaf(w4.y, xw1, a);
            a = fmaf(w4.z, xw2, a); a = fmaf(w4.w, x0, a);
            float uv = a * sigmoidf_(a);
            xw0 = xw1; xw1 = xw2; xw2 = x0;
            const float* xrow = xb + (size_t)t * 96;
            float4 B0 = *(const float4*)(xrow);
            float4 B1 = *(const float4*)(xrow + 4);
            float4 B2 = *(const float4*)(xrow + 8);
            float4 B3 = *(const float4*)(xrow + 12);
            float4 C0 = *(const float4*)(xrow + 16);
            float4 C1 = *(const float4*)(xrow + 20);
            float4 C2 = *(const float4*)(xrow + 24);
            float4 C3 = *(const float4*)(xrow + 28);
            float Bv[16] = {B0.x, B0.y, B0.z, B0.w, B1.x, B1.y, B1.z, B1.w,
                            B2.x, B2.y, B2.z, B2.w, B3.x, B3.y, B3.z, B3.w};
            float Cv[16] = {C0.x, C0.y, C0.z, C0.w, C1.x, C1.y, C1.z, C1.w,
                            C2.x, C2.y, C2.z, C2.w, C3.x, C3.y, C3.z, C3.w};
            float du = dv * uv;
            float q = __expf(-dv);
            float dA = q;
            float y = 0.0f;
            #pragma unroll
            for (int n = 0; n < D_STATE; ++n) {
                h[n] = fmaf(dA, h[n], du * Bv[n]);
                y = fmaf(h[n], Cv[n], y);
                dA *= q;
            }
            float zv = bf2f(zptr[(size_t)t * D_INNER]);
            float yg = (y + uv * D_e) * (zv * sigmoidf_(zv));
            yout[(size_t)t * D_INNER] = f2bf(yg);
        }
    } else {
        for (int t = 0; t < CHUNK; ++t) {
            float dv = bf2f(dptr[(size_t)t * D_INNER]);
            float x0 = bf2f(xptr[(size_t)t * D_INNER]);
            float a = cbv;
            a = fmaf(w4.x, xw0, a); a = fmaf(w4.y, xw1, a);
            a = fmaf(w4.z, xw2, a); a = fmaf(w4.w, x0, a);
            float uv = a * sigmoidf_(a);
            xw0 = xw1; xw1 = xw2; xw2 = x0;
            const float* xrow = xb + (size_t)t * 96;
            float4 B0 = *(const float4*)(xrow);
            float4 B1 = *(const float4*)(xrow + 4);
            float4 B2 = *(const float4*)(xrow + 8);
            float4 B3 = *(const float4*)(xrow + 12);
            float4 C0 = *(const float4*)(xrow + 16);
            float4 C1 = *(const float4*)(xrow + 20);
            float4 C2 = *(const float4*)(xrow + 24);
            float4 C3 = *(const float4*)(xrow + 28);
            float Bv[16] = {B0.x, B0.y, B0.z, B0.w, B1.x, B1.y, B1.z, B1.w,
                            B2.x, B2.y, B2.z, B2.w, B3.x, B3.y, B3.z, B3.w};
            float Cv[16] = {C0.x, C0.y, C0.z, C0.w, C1.x, C1.y, C1.z, C1.w,
                            C2.x, C2.y, C2.z, C2.w, C3.x, C3.y, C3.z, C3.w};
            float du = dv * uv;
            float y = 0.0f;
            #pragma unroll
            for (int n = 0; n < D_STATE; ++n) {
                float dA = __expf(dv * A_en[n]);
                h[n] = fmaf(dA, h[n], du * Bv[n]);
                y = fmaf(h[n], Cv[n], y);
            }
            float zv = bf2f(zptr[(size_t)t * D_INNER]);
            float yg = (y + uv * D_e) * (zv * sigmoidf_(zv));
            yout[(size_t)t * D_INNER] = f2bf(yg);
        }
    }
}

// ---------------------------------------------------------------------------
extern "C" void kernel_launch(void* const* d_in, const int* in_sizes, int n_in,
                              void* d_out, int out_size, void* d_ws, size_t ws_size,
                              hipStream_t stream) {
    const float* x      = (const float*)d_in[0];
    const float* W_in   = (const float*)d_in[1];
    const float* conv_w = (const float*)d_in[2];
    const float* conv_b = (const float*)d_in[3];
    const float* W_xp   = (const float*)d_in[4];
    const float* W_dt   = (const float*)d_in[5];
    const float* dt_b   = (const float*)d_in[6];
    const float* A_log  = (const float*)d_in[7];
    const float* D_skip = (const float*)d_in[8];
    const float* W_out  = (const float*)d_in[9];
    float* out = (float*)d_out;

    // workspace ledger (float units). Peak = 18M floats = 72 MB (< proven 76.8).
    //   xp_bf  (bf16) [0, 2M)                step1 -> p3
    //   hend   (bf16) [4M, 6M)               p1 -> p3
    //   Wint_bf(bf16) [6M, 8M)               prep -> step1
    //   delta  (bf16) [8M, 9M)               step4 -> p3
    //     xdbl_part   [8M, 11M) (alias f32)  step2 -> step3  (pre-step4, ok)
    //     out_part    [8M, 12M) (alias f32)  step6 -> step7  (delta dead after p3)
    //   z_bf   (bf16) [12M, 14M)             step1 -> p3
    //   x_dbl  (f32)  [14M, +196608)         step3 -> p3
    //   sumd   (f32)  [14M+262144, +262144)  p1 -> p2
    //   ybf    (bf16) [14M+524288, 16M+524288) p3 -> step6
    //     x_bf (bf16) [14M+524288, 15M+524288) (alias) prep -> step1
    //   Woutt  (bf16) [17M, 18M)             prep -> step6
    const size_t M1 = 1024 * 1024;
    float* ws = (float*)d_ws;
    ushort_t* xp_bf = (ushort_t*)ws;
    ushort_t* hend  = (ushort_t*)(ws + 4 * M1);
    ushort_t* Wint_bf = (ushort_t*)(ws + 6 * M1);
    ushort_t* delta = (ushort_t*)(ws + 8 * M1);
    ushort_t* z_bf  = (ushort_t*)(ws + 12 * M1);
    float*    x_dbl = ws + 14 * M1;
    float*    sumd  = ws + 14 * M1 + 262144;
    ushort_t* ybf   = (ushort_t*)(ws + 14 * M1 + 524288);
    float*    xdbl_part = ws + 8 * M1;
    float*    out_part  = ws + 8 * M1;
    ushort_t* x_bf  = ybf;
    ushort_t* Woutt_bf = (ushort_t*)(ws + 17 * M1);

    dim3 blk(256);

    // 0) merged prep: x->bf16, W_in^T, W_out^T
    hipLaunchKernelGGL(prep_kernel, dim3(1024 + 4096 + 2048), blk, 0, stream,
                       x, x_bf, W_in, Wint_bf, W_out, Woutt_bf);
    // 1) [xp(bf16) | z(bf16)] = x @ W_in  (64x128 tile, BK=32, 1024 blocks)
    hipLaunchKernelGGL((gemm_bf16_t<64, 128, 1, 1, 1, 1, 4, 32>),
                       dim3((BL / 64) * (4096 / 128)), blk, 0, stream,
                       x_bf, Wint_bf, (void*)xp_bf, (void*)z_bf,
                       BL, 2 * D_INNER, D_MODEL, D_INNER);
    // 2) x_dbl partials = silu(conv(xp)) @ W_xp   (conv fused, split-K)
    hipLaunchKernelGGL(gemm_xdbl_convfused, dim3(BL / 64, KSPLIT), blk, 0, stream,
                       xp_bf, W_xp, conv_w, conv_b, xdbl_part);
    // 3) reduce partials -> x_dbl
    hipLaunchKernelGGL(xdbl_reduce, dim3((BL * 96) / 256), blk, 0, stream,
                       xdbl_part, x_dbl);
    // 4) delta(bf16) = softplus(x_dbl[:, :64] @ W_dt + dt_bias)
    hipLaunchKernelGGL(gemm_delta, dim3(D_INNER / 64, BL / 64), blk, 0, stream,
                       x_dbl, W_dt, delta, dt_b, BL, D_INNER, DT_RANK, 96, D_INNER, D_INNER);
    // 5) chunked selective scan -> ybf
    hipLaunchKernelGGL(scan_phase1, dim3((BB * NCHUNK * D_INNER) / 256), blk, 0, stream,
                       delta, xp_bf, conv_w, conv_b, x_dbl, A_log, hend, sumd);
    hipLaunchKernelGGL(scan_phase2, dim3((BB * D_STATE * D_INNER) / 256), blk, 0, stream,
                       A_log, sumd, hend);
    hipLaunchKernelGGL(scan_phase3, dim3((BB * NCHUNK * D_INNER) / 256), blk, 0, stream,
                       delta, xp_bf, conv_w, conv_b, x_dbl, z_bf, A_log, D_skip, hend, ybf);
    // 6) out partials = ybf @ W_out  (64x64 tile, BK=32, split-K=2)
    hipLaunchKernelGGL((gemm_bf16_t<64, 64, 0, 0, 0, 2, 8, 32>),
                       dim3((BL / 64) * (D_MODEL / 64) * 2), blk, 0, stream,
                       ybf, Woutt_bf, (void*)out_part, (void*)out_part,
                       BL, D_MODEL, D_INNER, D_MODEL);
    // 7) reduce the two K-halves -> out
    hipLaunchKernelGGL(out_reduce, dim3((BL * D_MODEL) / (256 * 4)), blk, 0, stream,
                       out_part, out, BL * D_MODEL);
}

// Round 17
// 171.132 us; speedup vs baseline: 1.0110x; 1.0016x over previous
//
#include <hip/hip_runtime.h>
#include <math.h>

#define D_MODEL 1024
#define D_INNER 2048
#define D_STATE 16
#define D_CONV  4
#define DT_RANK 64
#define BB      2
#define LL      1024
#define BL      (BB*LL)   // 2048 rows (B*L)
#define CHUNK   16
#define NCHUNK  (LL/CHUNK)   // 64
#define KSPLIT  16           // split-K for x_dbl GEMM
#define KS_E    (D_INNER/KSPLIT)   // 128 e-cols per split

typedef __attribute__((ext_vector_type(8))) short short8;
typedef __attribute__((ext_vector_type(4))) float f32x4;
typedef unsigned short ushort_t;
typedef unsigned int uint_t;

__device__ __forceinline__ float sigmoidf_(float x) { return 1.0f / (1.0f + __expf(-x)); }

__device__ __forceinline__ ushort_t f2bf(float f) {
    uint_t u = __float_as_uint(f);
    uint_t r = (u + 0x7fffu + ((u >> 16) & 1u)) >> 16;
    return (ushort_t)r;
}
__device__ __forceinline__ float bf2f(ushort_t v) {
    return __uint_as_float((uint_t)v << 16);
}

__device__ __forceinline__ void gload_lds16(const void* g, void* l) {
    __builtin_amdgcn_global_load_lds(
        (const __attribute__((address_space(1))) void*)g,
        (__attribute__((address_space(3))) void*)l,
        16, 0, 0);
}

// ---------------------------------------------------------------------------
// bf16 MFMA GEMM, templated tile: C = A[M,K] @ Bt[N,K]^T.
// 4 waves as 2(M) x 2(N); BK in {32,64}; 16x16x32 MFMA. 1D grid, XCD-swizzled.
// SPLIT: col-split epilogue. BF0/BF1: outputs bf16. KSPL>1: split-K partials
// to C0v + kz*M*N (fp32). MINW: blocks/CU target.
// Measured optima: in_proj 64x128 BK=32 MINW=4; out_proj 64x64 BK=32 splitK=2.
// NOTE (R16): cooperative grid.sync scan fusion FAILS under the harness's
// graph capture (stale phase-1 data at replay) -- do not retry.
// ---------------------------------------------------------------------------
template<int BM, int BN, int SPLIT, int BF0, int BF1, int KSPL, int MINW, int BK>
__global__ __launch_bounds__(256, MINW)
void gemm_bf16_t(const ushort_t* __restrict__ A, const ushort_t* __restrict__ Bt,
                 void* __restrict__ C0v, void* __restrict__ C1v,
                 int M, int N, int K, int split) {
    constexpr int WMr = BM / 32;
    constexpr int WNr = BN / 32;
    constexpr int KSUB = BK / 32;
    const int nx = N / BN;
    const int per = nx * (M / BM);
    const int nwg = per * KSPL;
    const int wg = ((blockIdx.x & 7) * (nwg >> 3)) + (blockIdx.x >> 3);
    const int kz = (KSPL > 1) ? (wg / per) : 0;
    const int rem = (KSPL > 1) ? (wg % per) : wg;
    const int row0 = (rem / nx) * BM;
    const int col0 = (rem % nx) * BN;
    const int Kh = K / KSPL;
    const int koff = kz * Kh;

    __shared__ __align__(16) ushort_t As[BM * BK];
    __shared__ __align__(16) ushort_t Bs[BN * BK];

    const int tid  = threadIdx.x;
    const int lane = tid & 63;
    const int wave = tid >> 6;
    const int wr = wave >> 1, wc = wave & 1;

    f32x4 acc[WMr][WNr];
    #pragma unroll
    for (int m = 0; m < WMr; ++m)
        #pragma unroll
        for (int n = 0; n < WNr; ++n)
            acc[m][n] = (f32x4){0.f, 0.f, 0.f, 0.f};

    const ushort_t* Ablk = A  + (size_t)row0 * K + koff;
    const ushort_t* Bblk = Bt + (size_t)col0 * K + koff;

    for (int k0 = 0; k0 < Kh; k0 += BK) {
        if (BK == 32) {
            const int r_ld  = tid >> 2;
            const int c8_ld = (tid & 3) * 8;
            #pragma unroll
            for (int i = 0; i < BM / 64; ++i)
                gload_lds16(Ablk + (size_t)(i * 64 + r_ld) * K + k0 + c8_ld,
                            &As[(i * 64 + wave * 16) * 32]);
            #pragma unroll
            for (int i = 0; i < BN / 64; ++i)
                gload_lds16(Bblk + (size_t)(i * 64 + r_ld) * K + k0 + c8_ld,
                            &Bs[(i * 64 + wave * 16) * 32]);
        } else {   // BK == 64: 8 lanes/row, 32 rows per instruction
            const int r_ld  = tid >> 3;
            const int c8_ld = (tid & 7) * 8;
            #pragma unroll
            for (int i = 0; i < BM / 32; ++i)
                gload_lds16(Ablk + (size_t)(i * 32 + r_ld) * K + k0 + c8_ld,
                            &As[(i * 32 + wave * 8) * 64]);
            #pragma unroll
            for (int i = 0; i < BN / 32; ++i)
                gload_lds16(Bblk + (size_t)(i * 32 + r_ld) * K + k0 + c8_ld,
                            &Bs[(i * 32 + wave * 8) * 64]);
        }
        __syncthreads();

        short8 af[WMr][KSUB], bf[WNr][KSUB];
        const int fr = lane & 15;
        const int kb = (lane >> 4) * 8;
        #pragma unroll
        for (int m = 0; m < WMr; ++m)
            #pragma unroll
            for (int ks = 0; ks < KSUB; ++ks)
                af[m][ks] = *(const short8*)
                    &As[(wr * WMr * 16 + m * 16 + fr) * BK + ks * 32 + kb];
        #pragma unroll
        for (int n = 0; n < WNr; ++n)
            #pragma unroll
            for (int ks = 0; ks < KSUB; ++ks)
                bf[n][ks] = *(const short8*)
                    &Bs[(wc * WNr * 16 + n * 16 + fr) * BK + ks * 32 + kb];

        #pragma unroll
        for (int ks = 0; ks < KSUB; ++ks)
            #pragma unroll
            for (int m = 0; m < WMr; ++m)
                #pragma unroll
                for (int n = 0; n < WNr; ++n)
                    acc[m][n] = __builtin_amdgcn_mfma_f32_16x16x32_bf16(
                        af[m][ks], bf[n][ks], acc[m][n], 0, 0, 0);
        __syncthreads();
    }

    const int crow = (lane >> 4) * 4;
    const int ccol = lane & 15;

    if (KSPL > 1) {
        float* Cb = (float*)C0v + (size_t)kz * M * N;
        #pragma unroll
        for (int m = 0; m < WMr; ++m) {
            #pragma unroll
            for (int n = 0; n < WNr; ++n) {
                float* cp = Cb + (size_t)(row0 + wr * WMr * 16 + m * 16 + crow) * N
                               + col0 + wc * WNr * 16 + n * 16 + ccol;
                #pragma unroll
                for (int i = 0; i < 4; ++i)
                    cp[(size_t)i * N] = acc[m][n][i];
            }
        }
        return;
    }

    const bool second = SPLIT && (col0 >= split);
    const int ldc = second ? (N - split) : (SPLIT ? split : N);
    const int cb  = second ? (col0 - split) : col0;

    #pragma unroll
    for (int m = 0; m < WMr; ++m) {
        #pragma unroll
        for (int n = 0; n < WNr; ++n) {
            size_t base = (size_t)(row0 + wr * WMr * 16 + m * 16 + crow) * ldc
                          + cb + wc * WNr * 16 + n * 16 + ccol;
            if (second) {
                if (BF1) { ushort_t* cp = (ushort_t*)C1v + base;
                    #pragma unroll
                    for (int i = 0; i < 4; ++i) cp[(size_t)i * ldc] = f2bf(acc[m][n][i]);
                } else { float* cp = (float*)C1v + base;
                    #pragma unroll
                    for (int i = 0; i < 4; ++i) cp[(size_t)i * ldc] = acc[m][n][i];
                }
            } else {
                if (BF0) { ushort_t* cp = (ushort_t*)C0v + base;
                    #pragma unroll
                    for (int i = 0; i < 4; ++i) cp[(size_t)i * ldc] = f2bf(acc[m][n][i]);
                } else { float* cp = (float*)C0v + base;
                    #pragma unroll
                    for (int i = 0; i < 4; ++i) cp[(size_t)i * ldc] = acc[m][n][i];
                }
            }
        }
    }
}

__global__ __launch_bounds__(256)
void out_reduce(const float* __restrict__ part, float* __restrict__ out, int n) {
    int i = (blockIdx.x * 256 + threadIdx.x) * 4;
    if (i + 4 <= n) {
        float4 a = *reinterpret_cast<const float4*>(part + i);
        float4 b = *reinterpret_cast<const float4*>(part + n + i);
        float4 r = {a.x + b.x, a.y + b.y, a.z + b.z, a.w + b.w};
        *reinterpret_cast<float4*>(out + i) = r;
    }
}

// ---------------------------------------------------------------------------
// Merged prep: job A (1024 blocks) x->bf16; job B (4096) W_in^T; job C (2048) W_out^T.
// ---------------------------------------------------------------------------
__device__ __forceinline__ void transp_tile_body(const float* __restrict__ W,
                                                 ushort_t* __restrict__ Wt,
                                                 int R, int C, int bx, int by,
                                                 ushort_t (*tile)[33]) {
    int tx = threadIdx.x & 31, ty = threadIdx.x >> 5;
    int r0 = by * 32, c0 = bx * 32;
    #pragma unroll
    for (int i = 0; i < 32; i += 8)
        tile[ty + i][tx] = f2bf(W[(size_t)(r0 + ty + i) * C + c0 + tx]);
    __syncthreads();
    #pragma unroll
    for (int i = 0; i < 32; i += 8)
        Wt[(size_t)(c0 + ty + i) * R + r0 + tx] = tile[tx][ty + i];
}

__global__ __launch_bounds__(256)
void prep_kernel(const float* __restrict__ x, ushort_t* __restrict__ x_bf,
                 const float* __restrict__ W_in, ushort_t* __restrict__ Wint,
                 const float* __restrict__ W_out, ushort_t* __restrict__ Woutt) {
    __shared__ ushort_t tile[32][33];
    int bid = blockIdx.x;
    if (bid < 1024) {
        int i = (bid * 256 + threadIdx.x) * 8;
        float4 a = *reinterpret_cast<const float4*>(x + i);
        float4 b = *reinterpret_cast<const float4*>(x + i + 4);
        ushort_t o[8] = {f2bf(a.x), f2bf(a.y), f2bf(a.z), f2bf(a.w),
                         f2bf(b.x), f2bf(b.y), f2bf(b.z), f2bf(b.w)};
        *reinterpret_cast<short8*>(x_bf + i) = *reinterpret_cast<short8*>(o);
    } else if (bid < 1024 + 4096) {
        int bi = bid - 1024;
        transp_tile_body(W_in, Wint, 1024, 4096, bi & 127, bi >> 7, tile);
    } else {
        int bi = bid - 5120;
        transp_tile_body(W_out, Woutt, 2048, 1024, bi & 31, bi >> 5, tile);
    }
}

// ---------------------------------------------------------------------------
// Split-K GEMM for x_dbl with FUSED depthwise conv + SiLU (xp in bf16):
// ---------------------------------------------------------------------------
__global__ __launch_bounds__(256)
void gemm_xdbl_convfused(const ushort_t* __restrict__ xp, const float* __restrict__ W,
                         const float* __restrict__ conv_w, const float* __restrict__ conv_b,
                         float* __restrict__ part) {
    __shared__ float Ax[16][68];
    __shared__ float Au[16][65];
    __shared__ float Bs[16][96];

    const int tid = threadIdx.x;
    const int m0 = blockIdx.x * 64;
    const int kbase = blockIdx.y * KS_E;
    const int tx = tid & 15;
    const int ty = tid >> 4;
    const bool bhead = (m0 & (LL - 1)) == 0;

    float acc[4][6] = {};

    for (int k0 = 0; k0 < KS_E; k0 += 16) {
        for (int i = tid; i < 67 * 16; i += 256) {
            int r = i >> 4, k = i & 15;
            float v = 0.f;
            if (!(bhead && r < 3))
                v = bf2f(xp[(size_t)(m0 - 3 + r) * D_INNER + kbase + k0 + k]);
            Ax[k][r] = v;
        }
        #pragma unroll
        for (int j = 0; j < 6; ++j) {
            int idx = j * 256 + tid;
            int row = idx / 96, col = idx - row * 96;
            Bs[row][col] = W[(size_t)(kbase + k0 + row) * 96 + col];
        }
        __syncthreads();
        {
            float4 w4 = *(const float4*)&conv_w[(size_t)(kbase + k0 + tx) * 4];
            float cbv = conv_b[kbase + k0 + tx];
            #pragma unroll
            for (int rr = 0; rr < 4; ++rr) {
                int r = ty + rr * 16;
                float a = cbv;
                a = fmaf(w4.x, Ax[tx][r], a);
                a = fmaf(w4.y, Ax[tx][r + 1], a);
                a = fmaf(w4.z, Ax[tx][r + 2], a);
                a = fmaf(w4.w, Ax[tx][r + 3], a);
                Au[tx][r] = a * sigmoidf_(a);
            }
        }
        __syncthreads();
        #pragma unroll
        for (int kk = 0; kk < 16; ++kk) {
            float a[4], b[6];
            #pragma unroll
            for (int i = 0; i < 4; ++i) a[i] = Au[kk][ty * 4 + i];
            #pragma unroll
            for (int j = 0; j < 6; ++j) b[j] = Bs[kk][tx * 6 + j];
            #pragma unroll
            for (int i = 0; i < 4; ++i)
                #pragma unroll
                for (int j = 0; j < 6; ++j)
                    acc[i][j] = fmaf(a[i], b[j], acc[i][j]);
        }
        __syncthreads();
    }

    float* pblk = part + (size_t)blockIdx.y * BL * 96;
    #pragma unroll
    for (int i = 0; i < 4; ++i)
        #pragma unroll
        for (int j = 0; j < 6; ++j)
            pblk[(size_t)(m0 + ty * 4 + i) * 96 + tx * 6 + j] = acc[i][j];
}

__global__ __launch_bounds__(256)
void xdbl_reduce(const float* __restrict__ part, float* __restrict__ x_dbl) {
    int i = blockIdx.x * 256 + threadIdx.x;
    float s = 0.0f;
    #pragma unroll
    for (int k = 0; k < KSPLIT; ++k)
        s += part[(size_t)k * BL * 96 + i];
    x_dbl[i] = s;
}

// ---------------------------------------------------------------------------
// Delta GEMM: delta(bf16) = softplus(x_dbl[:, :64] @ W_dt + dt_bias).
// ---------------------------------------------------------------------------
__global__ __launch_bounds__(256)
void gemm_delta(const float* __restrict__ A, const float* __restrict__ B,
                ushort_t* __restrict__ C, const float* __restrict__ bias,
                int M, int N, int K, int lda, int ldb, int ldc) {
    __shared__ float As[16][65];
    __shared__ float Bs[16][64];

    const int tid = threadIdx.x;
    const int tx = tid & 15;
    const int ty = tid >> 4;
    const int row0 = blockIdx.y * 64;
    const int col0 = blockIdx.x * 64;

    const int arow = tid >> 4;
    const int acol = tid & 15;
    const int brow = tid >> 6;
    const int bcol = tid & 63;

    float acc[4][4] = {};

    for (int k0 = 0; k0 < K; k0 += 16) {
        #pragma unroll
        for (int p = 0; p < 4; ++p) {
            int r = arow + p * 16;
            As[acol][r] = A[(size_t)(row0 + r) * lda + (k0 + acol)];
        }
        int gc = col0 + bcol;
        #pragma unroll
        for (int p = 0; p < 4; ++p) {
            int r = brow + p * 4;
            Bs[r][bcol] = B[(size_t)(k0 + r) * ldb + gc];
        }
        __syncthreads();
        #pragma unroll
        for (int kk = 0; kk < 16; ++kk) {
            float a[4];
            #pragma unroll
            for (int i = 0; i < 4; ++i) a[i] = As[kk][ty * 4 + i];
            float4 bv = *reinterpret_cast<const float4*>(&Bs[kk][tx * 4]);
            float b4[4] = {bv.x, bv.y, bv.z, bv.w};
            #pragma unroll
            for (int i = 0; i < 4; ++i)
                #pragma unroll
                for (int j = 0; j < 4; ++j)
                    acc[i][j] = fmaf(a[i], b4[j], acc[i][j]);
        }
        __syncthreads();
    }

    #pragma unroll
    for (int i = 0; i < 4; ++i) {
        int gr = row0 + ty * 4 + i;
        #pragma unroll
        for (int j = 0; j < 4; ++j) {
            int gc = col0 + tx * 4 + j;
            float v = acc[i][j] + bias[gc];
            v = (v > 20.0f) ? v : log1pf(__expf(v));
            C[(size_t)gr * ldc + gc] = f2bf(v);
        }
    }
}

// ---------------------------------------------------------------------------
// Chunked selective scan (delta/xp/hend bf16, conv fused, geo fast path).
// g = [b:1][c:6][e:11]. hend layout: [c][b][n][e]. sumdelta: [c][b][e].
// ---------------------------------------------------------------------------
__global__ __launch_bounds__(256)
void scan_phase1(const ushort_t* __restrict__ delta, const ushort_t* __restrict__ xp,
                 const float* __restrict__ conv_w, const float* __restrict__ conv_b,
                 const float* __restrict__ x_dbl, const float* __restrict__ A_log,
                 ushort_t* __restrict__ hend, float* __restrict__ sumdelta) {
    int g = blockIdx.x * 256 + threadIdx.x;
    int e = g & (D_INNER - 1);
    int c = (g >> 11) & (NCHUNK - 1);
    int b = g >> 17;

    float A_en[D_STATE];
    bool geo = true;
    #pragma unroll
    for (int n = 0; n < D_STATE; n += 4) {
        float4 al = *(const float4*)&A_log[e * D_STATE + n];
        A_en[n]     = -__expf(al.x);
        A_en[n + 1] = -__expf(al.y);
        A_en[n + 2] = -__expf(al.z);
        A_en[n + 3] = -__expf(al.w);
    }
    #pragma unroll
    for (int n = 0; n < D_STATE; ++n)
        geo = geo && (fabsf(A_en[n] + (float)(n + 1)) <= 2e-5f * (float)(n + 1));

    const int t0 = c * CHUNK;
    const ushort_t* dptr = delta + (size_t)(b * LL + t0) * D_INNER + e;
    const ushort_t* xptr = xp + (size_t)(b * LL + t0) * D_INNER + e;
    const float* xb   = x_dbl + (size_t)(b * LL + t0) * 96 + DT_RANK;
    float4 w4 = *(const float4*)&conv_w[(size_t)e * 4];
    float cbv = conv_b[e];

    float xw0 = 0.f, xw1 = 0.f, xw2 = 0.f;
    if (c > 0) {
        xw0 = bf2f(xptr[-3 * D_INNER]);
        xw1 = bf2f(xptr[-2 * D_INNER]);
        xw2 = bf2f(xptr[-1 * D_INNER]);
    }

    float h[D_STATE];
    #pragma unroll
    for (int n = 0; n < D_STATE; ++n) h[n] = 0.0f;
    float S = 0.0f;

    if (geo) {
        #pragma unroll 2
        for (int t = 0; t < CHUNK; ++t) {
            float dv = bf2f(dptr[(size_t)t * D_INNER]);
            float x0 = bf2f(xptr[(size_t)t * D_INNER]);
            float a = cbv;
            a = fmaf(w4.x, xw0, a); a = fmaf(w4.y, xw1, a);
            a = fmaf(w4.z, xw2, a); a = fmaf(w4.w, x0, a);
            float uv = a * sigmoidf_(a);
            xw0 = xw1; xw1 = xw2; xw2 = x0;
            const float* xrow = xb + (size_t)t * 96;
            float4 B0 = *(const float4*)(xrow);
            float4 B1 = *(const float4*)(xrow + 4);
            float4 B2 = *(const float4*)(xrow + 8);
            float4 B3 = *(const float4*)(xrow + 12);
            float Bv[16] = {B0.x, B0.y, B0.z, B0.w, B1.x, B1.y, B1.z, B1.w,
                            B2.x, B2.y, B2.z, B2.w, B3.x, B3.y, B3.z, B3.w};
            S += dv;
            float du = dv * uv;
            float q = __expf(-dv);
            float dA = q;
            #pragma unroll
            for (int n = 0; n < D_STATE; ++n) {
                h[n] = fmaf(dA, h[n], du * Bv[n]);
                dA *= q;
            }
        }
    } else {
        for (int t = 0; t < CHUNK; ++t) {
            float dv = bf2f(dptr[(size_t)t * D_INNER]);
            float x0 = bf2f(xptr[(size_t)t * D_INNER]);
            float a = cbv;
            a = fmaf(w4.x, xw0, a); a = fmaf(w4.y, xw1, a);
            a = fmaf(w4.z, xw2, a); a = fmaf(w4.w, x0, a);
            float uv = a * sigmoidf_(a);
            xw0 = xw1; xw1 = xw2; xw2 = x0;
            const float* xrow = xb + (size_t)t * 96;
            float4 B0 = *(const float4*)(xrow);
            float4 B1 = *(const float4*)(xrow + 4);
            float4 B2 = *(const float4*)(xrow + 8);
            float4 B3 = *(const float4*)(xrow + 12);
            float Bv[16] = {B0.x, B0.y, B0.z, B0.w, B1.x, B1.y, B1.z, B1.w,
                            B2.x, B2.y, B2.z, B2.w, B3.x, B3.y, B3.z, B3.w};
            S += dv;
            float du = dv * uv;
            #pragma unroll
            for (int n = 0; n < D_STATE; ++n) {
                float dA = __expf(dv * A_en[n]);
                h[n] = fmaf(dA, h[n], du * Bv[n]);
            }
        }
    }

    size_t rbase = ((size_t)(c * BB + b) * D_STATE) * D_INNER + e;
    #pragma unroll
    for (int n = 0; n < D_STATE; ++n)
        hend[rbase + (size_t)n * D_INNER] = f2bf(h[n]);
    sumdelta[(size_t)(c * BB + b) * D_INNER + e] = S;
}

// In-place: hh holds hend(bf16) on entry, hin(bf16) on exit.
// 4x unrolled: 8 independent loads + 4 exps issue ahead of the 4-fma chain.
__global__ __launch_bounds__(256)
void scan_phase2(const float* __restrict__ A_log, const float* __restrict__ sumdelta,
                 ushort_t* __restrict__ hh) {
    int g = blockIdx.x * 256 + threadIdx.x;
    int e = g & (D_INNER - 1);
    int n = (g >> 11) & (D_STATE - 1);
    int b = g >> 15;
    float A_en = -__expf(A_log[e * D_STATE + n]);
    float np1 = (float)(n + 1);
    if (fabsf(A_en + np1) <= 2e-5f * np1) A_en = -np1;

    const size_t CS = (size_t)BB * D_STATE * D_INNER;   // hh stride per chunk
    const size_t DS = (size_t)BB * D_INNER;             // sumd stride per chunk
    size_t hidx = ((size_t)b * D_STATE + n) * D_INNER + e;
    size_t didx = (size_t)b * D_INNER + e;

    float h = 0.0f;
    #pragma unroll 1
    for (int c = 0; c < NCHUNK; c += 4) {
        float he0 = bf2f(hh[hidx]);
        float he1 = bf2f(hh[hidx + CS]);
        float he2 = bf2f(hh[hidx + 2 * CS]);
        float he3 = bf2f(hh[hidx + 3 * CS]);
        float q0 = __expf(A_en * sumdelta[didx]);
        float q1 = __expf(A_en * sumdelta[didx + DS]);
        float q2 = __expf(A_en * sumdelta[didx + 2 * DS]);
        float q3 = __expf(A_en * sumdelta[didx + 3 * DS]);
        hh[hidx] = f2bf(h);          h = fmaf(q0, h, he0);
        hh[hidx + CS] = f2bf(h);     h = fmaf(q1, h, he1);
        hh[hidx + 2 * CS] = f2bf(h); h = fmaf(q2, h, he2);
        hh[hidx + 3 * CS] = f2bf(h); h = fmaf(q3, h, he3);
        hidx += 4 * CS;
        didx += 4 * DS;
    }
}

__global__ __launch_bounds__(256)
void scan_phase3(const ushort_t* __restrict__ delta, const ushort_t* __restrict__ xp,
                 const float* __restrict__ conv_w, const float* __restrict__ conv_b,
                 const float* __restrict__ x_dbl, const ushort_t* __restrict__ zbf,
                 const float* __restrict__ A_log, const float* __restrict__ D_skip,
                 const ushort_t* __restrict__ hin, ushort_t* __restrict__ ybf) {
    int g = blockIdx.x * 256 + threadIdx.x;
    int e = g & (D_INNER - 1);
    int c = (g >> 11) & (NCHUNK - 1);
    int b = g >> 17;

    float A_en[D_STATE];
    bool geo = true;
    #pragma unroll
    for (int n = 0; n < D_STATE; n += 4) {
        float4 al = *(const float4*)&A_log[e * D_STATE + n];
        A_en[n]     = -__expf(al.x);
        A_en[n + 1] = -__expf(al.y);
        A_en[n + 2] = -__expf(al.z);
        A_en[n + 3] = -__expf(al.w);
    }
    #pragma unroll
    for (int n = 0; n < D_STATE; ++n)
        geo = geo && (fabsf(A_en[n] + (float)(n + 1)) <= 2e-5f * (float)(n + 1));

    float D_e = D_skip[e];
    float h[D_STATE];
    size_t rbase = ((size_t)(c * BB + b) * D_STATE) * D_INNER + e;
    #pragma unroll
    for (int n = 0; n < D_STATE; ++n)
        h[n] = bf2f(hin[rbase + (size_t)n * D_INNER]);

    const int t0 = c * CHUNK;
    const ushort_t* dptr = delta + (size_t)(b * LL + t0) * D_INNER + e;
    const ushort_t* xptr = xp + (size_t)(b * LL + t0) * D_INNER + e;
    const float* xb   = x_dbl + (size_t)(b * LL + t0) * 96 + DT_RANK;
    const ushort_t* zptr = zbf + (size_t)(b * LL + t0) * D_INNER + e;
    ushort_t* yout = ybf + (size_t)(b * LL + t0) * D_INNER + e;
    float4 w4 = *(const float4*)&conv_w[(size_t)e * 4];
    float cbv = conv_b[e];

    float xw0 = 0.f, xw1 = 0.f, xw2 = 0.f;
    if (c > 0) {
        xw0 = bf2f(xptr[-3 * D_INNER]);
        xw1 = bf2f(xptr[-2 * D_INNER]);
        xw2 = bf2f(xptr[-1 * D_INNER]);
    }

    if (geo) {
        #pragma unroll 2
        for (int t = 0; t < CHUNK; ++t) {
            float dv = bf2f(dptr[(size_t)t * D_INNER]);
            float x0 = bf2f(xptr[(size_t)t * D_INNER]);
            float a = cbv;
            a = fmaf(w4.x, xw0, a); a = fmaf(w4.y, xw1, a);
            a = fmaf(w4.z, xw2, a); a = fmaf(w4.w, x0, a);
            float uv = a * sigmoidf_(a);
            xw0 = xw1; xw1 = xw2; xw2 = x0;
            const float* xrow = xb + (size_t)t * 96;
            float4 B0 = *(const float4*)(xrow);
            float4 B1 = *(const float4*)(xrow + 4);
            float4 B2 = *(const float4*)(xrow + 8);
            float4 B3 = *(const float4*)(xrow + 12);
            float4 C0 = *(const float4*)(xrow + 16);
            float4 C1 = *(const float4*)(xrow + 20);
            float4 C2 = *(const float4*)(xrow + 24);
            float4 C3 = *(const float4*)(xrow + 28);
            float Bv[16] = {B0.x, B0.y, B0.z, B0.w, B1.x, B1.y, B1.z, B1.w,
                            B2.x, B2.y, B2.z, B2.w, B3.x, B3.y, B3.z, B3.w};
            float Cv[16] = {C0.x, C0.y, C0.z, C0.w, C1.x, C1.y, C1.z, C1.w,
                            C2.x, C2.y, C2.z, C2.w, C3.x, C3.y, C3.z, C3.w};
            float du = dv * uv;
            float q = __expf(-dv);
            float dA = q;
            float y = 0.0f;
            #pragma unroll
            for (int n = 0; n < D_STATE; ++n) {
                h[n] = fmaf(dA, h[n], du * Bv[n]);
                y = fmaf(h[n], Cv[n], y);
                dA *= q;
            }
            float zv = bf2f(zptr[(size_t)t * D_INNER]);
            float yg = (y + uv * D_e) * (zv * sigmoidf_(zv));
            yout[(size_t)t * D_INNER] = f2bf(yg);
        }
    } else {
        for (int t = 0; t < CHUNK; ++t) {
            float dv = bf2f(dptr[(size_t)t * D_INNER]);
            float x0 = bf2f(xptr[(size_t)t * D_INNER]);
            float a = cbv;
            a = fmaf(w4.x, xw0, a); a = fmaf(w4.y, xw1, a);
            a = fmaf(w4.z, xw2, a); a = fmaf(w4.w, x0, a);
            float uv = a * sigmoidf_(a);
            xw0 = xw1; xw1 = xw2; xw2 = x0;
            const float* xrow = xb + (size_t)t * 96;
            float4 B0 = *(const float4*)(xrow);
            float4 B1 = *(const float4*)(xrow + 4);
            float4 B2 = *(const float4*)(xrow + 8);
            float4 B3 = *(const float4*)(xrow + 12);
            float4 C0 = *(const float4*)(xrow + 16);
            float4 C1 = *(const float4*)(xrow + 20);
            float4 C2 = *(const float4*)(xrow + 24);
            float4 C3 = *(const float4*)(xrow + 28);
            float Bv[16] = {B0.x, B0.y, B0.z, B0.w, B1.x, B1.y, B1.z, B1.w,
                            B2.x, B2.y, B2.z, B2.w, B3.x, B3.y, B3.z, B3.w};
            float Cv[16] = {C0.x, C0.y, C0.z, C0.w, C1.x, C1.y, C1.z, C1.w,
                            C2.x, C2.y, C2.z, C2.w, C3.x, C3.y, C3.z, C3.w};
            float du = dv * uv;
            float y = 0.0f;
            #pragma unroll
            for (int n = 0; n < D_STATE; ++n) {
                float dA = __expf(dv * A_en[n]);
                h[n] = fmaf(dA, h[n], du * Bv[n]);
                y = fmaf(h[n], Cv[n], y);
            }
            float zv = bf2f(zptr[(size_t)t * D_INNER]);
            float yg = (y + uv * D_e) * (zv * sigmoidf_(zv));
            yout[(size_t)t * D_INNER] = f2bf(yg);
        }
    }
}

// ---------------------------------------------------------------------------
extern "C" void kernel_launch(void* const* d_in, const int* in_sizes, int n_in,
                              void* d_out, int out_size, void* d_ws, size_t ws_size,
                              hipStream_t stream) {
    const float* x      = (const float*)d_in[0];
    const float* W_in   = (const float*)d_in[1];
    const float* conv_w = (const float*)d_in[2];
    const float* conv_b = (const float*)d_in[3];
    const float* W_xp   = (const float*)d_in[4];
    const float* W_dt   = (const float*)d_in[5];
    const float* dt_b   = (const float*)d_in[6];
    const float* A_log  = (const float*)d_in[7];
    const float* D_skip = (const float*)d_in[8];
    const float* W_out  = (const float*)d_in[9];
    float* out = (float*)d_out;

    // workspace ledger (float units). Peak = 18M floats = 72 MB (< proven 76.8).
    //   xp_bf  (bf16) [0, 2M)                step1 -> p3
    //   hend   (bf16) [4M, 6M)               p1 -> p3
    //   Wint_bf(bf16) [6M, 8M)               prep -> step1
    //   delta  (bf16) [8M, 9M)               step4 -> p3
    //     xdbl_part   [8M, 11M) (alias f32)  step2 -> step3  (pre-step4, ok)
    //     out_part    [8M, 12M) (alias f32)  step6 -> step7  (delta dead after p3)
    //   z_bf   (bf16) [12M, 14M)             step1 -> p3
    //   x_dbl  (f32)  [14M, +196608)         step3 -> p3
    //   sumd   (f32)  [14M+262144, +262144)  p1 -> p2
    //   ybf    (bf16) [14M+524288, 16M+524288) p3 -> step6
    //     x_bf (bf16) [14M+524288, 15M+524288) (alias) prep -> step1
    //   Woutt  (bf16) [17M, 18M)             prep -> step6
    const size_t M1 = 1024 * 1024;
    float* ws = (float*)d_ws;
    ushort_t* xp_bf = (ushort_t*)ws;
    ushort_t* hend  = (ushort_t*)(ws + 4 * M1);
    ushort_t* Wint_bf = (ushort_t*)(ws + 6 * M1);
    ushort_t* delta = (ushort_t*)(ws + 8 * M1);
    ushort_t* z_bf  = (ushort_t*)(ws + 12 * M1);
    float*    x_dbl = ws + 14 * M1;
    float*    sumd  = ws + 14 * M1 + 262144;
    ushort_t* ybf   = (ushort_t*)(ws + 14 * M1 + 524288);
    float*    xdbl_part = ws + 8 * M1;
    float*    out_part  = ws + 8 * M1;
    ushort_t* x_bf  = ybf;
    ushort_t* Woutt_bf = (ushort_t*)(ws + 17 * M1);

    dim3 blk(256);

    // 0) merged prep: x->bf16, W_in^T, W_out^T
    hipLaunchKernelGGL(prep_kernel, dim3(1024 + 4096 + 2048), blk, 0, stream,
                       x, x_bf, W_in, Wint_bf, W_out, Woutt_bf);
    // 1) [xp(bf16) | z(bf16)] = x @ W_in  (64x128 tile, BK=32, 1024 blocks)
    hipLaunchKernelGGL((gemm_bf16_t<64, 128, 1, 1, 1, 1, 4, 32>),
                       dim3((BL / 64) * (4096 / 128)), blk, 0, stream,
                       x_bf, Wint_bf, (void*)xp_bf, (void*)z_bf,
                       BL, 2 * D_INNER, D_MODEL, D_INNER);
    // 2) x_dbl partials = silu(conv(xp)) @ W_xp   (conv fused, split-K)
    hipLaunchKernelGGL(gemm_xdbl_convfused, dim3(BL / 64, KSPLIT), blk, 0, stream,
                       xp_bf, W_xp, conv_w, conv_b, xdbl_part);
    // 3) reduce partials -> x_dbl
    hipLaunchKernelGGL(xdbl_reduce, dim3((BL * 96) / 256), blk, 0, stream,
                       xdbl_part, x_dbl);
    // 4) delta(bf16) = softplus(x_dbl[:, :64] @ W_dt + dt_bias)
    hipLaunchKernelGGL(gemm_delta, dim3(D_INNER / 64, BL / 64), blk, 0, stream,
                       x_dbl, W_dt, delta, dt_b, BL, D_INNER, DT_RANK, 96, D_INNER, D_INNER);
    // 5) chunked selective scan -> ybf
    hipLaunchKernelGGL(scan_phase1, dim3((BB * NCHUNK * D_INNER) / 256), blk, 0, stream,
                       delta, xp_bf, conv_w, conv_b, x_dbl, A_log, hend, sumd);
    hipLaunchKernelGGL(scan_phase2, dim3((BB * D_STATE * D_INNER) / 256), blk, 0, stream,
                       A_log, sumd, hend);
    hipLaunchKernelGGL(scan_phase3, dim3((BB * NCHUNK * D_INNER) / 256), blk, 0, stream,
                       delta, xp_bf, conv_w, conv_b, x_dbl, z_bf, A_log, D_skip, hend, ybf);
    // 6) out partials = ybf @ W_out  (64x64 tile, BK=32, split-K=2)
    hipLaunchKernelGGL((gemm_bf16_t<64, 64, 0, 0, 0, 2, 8, 32>),
                       dim3((BL / 64) * (D_MODEL / 64) * 2), blk, 0, stream,
                       ybf, Woutt_bf, (void*)out_part, (void*)out_part,
                       BL, D_MODEL, D_INNER, D_MODEL);
    // 7) reduce the two K-halves -> out
    hipLaunchKernelGGL(out_reduce, dim3((BL * D_MODEL) / (256 * 4)), blk, 0, stream,
                       out_part, out, BL * D_MODEL);
}

// Round 18
// 169.316 us; speedup vs baseline: 1.0218x; 1.0107x over previous
//
#include <hip/hip_runtime.h>
#include <math.h>

#define D_MODEL 1024
#define D_INNER 2048
#define D_STATE 16
#define D_CONV  4
#define DT_RANK 64
#define BB      2
#define LL      1024
#define BL      (BB*LL)   // 2048 rows (B*L)
#define CHUNK   16
#define NCHUNK  (LL/CHUNK)   // 64
#define KSPLIT  16           // split-K for x_dbl GEMM
#define KS_E    (D_INNER/KSPLIT)   // 128 e-cols per split

typedef __attribute__((ext_vector_type(8))) short short8;
typedef __attribute__((ext_vector_type(4))) float f32x4;
typedef unsigned short ushort_t;
typedef unsigned int uint_t;

__device__ __forceinline__ float sigmoidf_(float x) { return 1.0f / (1.0f + __expf(-x)); }

__device__ __forceinline__ ushort_t f2bf(float f) {
    uint_t u = __float_as_uint(f);
    uint_t r = (u + 0x7fffu + ((u >> 16) & 1u)) >> 16;
    return (ushort_t)r;
}
__device__ __forceinline__ float bf2f(ushort_t v) {
    return __uint_as_float((uint_t)v << 16);
}

__device__ __forceinline__ void gload_lds16(const void* g, void* l) {
    __builtin_amdgcn_global_load_lds(
        (const __attribute__((address_space(1))) void*)g,
        (__attribute__((address_space(3))) void*)l,
        16, 0, 0);
}

// ---------------------------------------------------------------------------
// bf16 MFMA GEMM, templated tile: C = A[M,K] @ Bt[N,K]^T.
// 4 waves as 2(M) x 2(N); BK=32; 16x16x32 MFMA. 1D grid, XCD-swizzled.
// SPLIT: col-split epilogue. BF0/BF1: outputs bf16. KSPL>1: split-K partials
// to C0v + kz*M*N (fp32). MINW: blocks/CU target.
// R18: 8x8-tile SUPERTILE chunking -- each XCD's contiguous wg range maps to
// whole 8x8 chunks (64 wgs), bounding per-XCD L2 working set to
// 512 rows * K * 2B (A) + 8*BN cols * K * 2B (B) ~ 3 MB < 4 MB L2.
// (Old row-major strip made every XCD stream all of B: 35-54 MB FETCH.)
// NOTE (R16): cooperative grid.sync scan fusion FAILS under graph capture.
// ---------------------------------------------------------------------------
template<int BM, int BN, int SPLIT, int BF0, int BF1, int KSPL, int MINW, int BK>
__global__ __launch_bounds__(256, MINW)
void gemm_bf16_t(const ushort_t* __restrict__ A, const ushort_t* __restrict__ Bt,
                 void* __restrict__ C0v, void* __restrict__ C1v,
                 int M, int N, int K, int split) {
    constexpr int WMr = BM / 32;
    constexpr int WNr = BN / 32;
    constexpr int KSUB = BK / 32;
    const int nx = N / BN;
    const int ny = M / BM;
    const int per = nx * ny;
    const int nwg = per * KSPL;
    const int wg = ((blockIdx.x & 7) * (nwg >> 3)) + (blockIdx.x >> 3);
    const int kz = (KSPL > 1) ? (wg / per) : 0;
    const int rem = (KSPL > 1) ? (wg % per) : wg;

    int row_t, col_t;
    if ((ny & 7) == 0 && (nx & 7) == 0) {   // 8x8 supertile chunking
        const int chunk = rem >> 6;
        const int within = rem & 63;
        const int ncx = nx >> 3;
        row_t = (chunk / ncx) * 8 + (within >> 3);
        col_t = (chunk % ncx) * 8 + (within & 7);
    } else {
        row_t = rem / nx;
        col_t = rem % nx;
    }
    const int row0 = row_t * BM;
    const int col0 = col_t * BN;
    const int Kh = K / KSPL;
    const int koff = kz * Kh;

    __shared__ __align__(16) ushort_t As[BM * BK];
    __shared__ __align__(16) ushort_t Bs[BN * BK];

    const int tid  = threadIdx.x;
    const int lane = tid & 63;
    const int wave = tid >> 6;
    const int wr = wave >> 1, wc = wave & 1;

    f32x4 acc[WMr][WNr];
    #pragma unroll
    for (int m = 0; m < WMr; ++m)
        #pragma unroll
        for (int n = 0; n < WNr; ++n)
            acc[m][n] = (f32x4){0.f, 0.f, 0.f, 0.f};

    const ushort_t* Ablk = A  + (size_t)row0 * K + koff;
    const ushort_t* Bblk = Bt + (size_t)col0 * K + koff;

    for (int k0 = 0; k0 < Kh; k0 += BK) {
        if (BK == 32) {
            const int r_ld  = tid >> 2;
            const int c8_ld = (tid & 3) * 8;
            #pragma unroll
            for (int i = 0; i < BM / 64; ++i)
                gload_lds16(Ablk + (size_t)(i * 64 + r_ld) * K + k0 + c8_ld,
                            &As[(i * 64 + wave * 16) * 32]);
            #pragma unroll
            for (int i = 0; i < BN / 64; ++i)
                gload_lds16(Bblk + (size_t)(i * 64 + r_ld) * K + k0 + c8_ld,
                            &Bs[(i * 64 + wave * 16) * 32]);
        } else {
            const int r_ld  = tid >> 3;
            const int c8_ld = (tid & 7) * 8;
            #pragma unroll
            for (int i = 0; i < BM / 32; ++i)
                gload_lds16(Ablk + (size_t)(i * 32 + r_ld) * K + k0 + c8_ld,
                            &As[(i * 32 + wave * 8) * 64]);
            #pragma unroll
            for (int i = 0; i < BN / 32; ++i)
                gload_lds16(Bblk + (size_t)(i * 32 + r_ld) * K + k0 + c8_ld,
                            &Bs[(i * 32 + wave * 8) * 64]);
        }
        __syncthreads();

        short8 af[WMr][KSUB], bf[WNr][KSUB];
        const int fr = lane & 15;
        const int kb = (lane >> 4) * 8;
        #pragma unroll
        for (int m = 0; m < WMr; ++m)
            #pragma unroll
            for (int ks = 0; ks < KSUB; ++ks)
                af[m][ks] = *(const short8*)
                    &As[(wr * WMr * 16 + m * 16 + fr) * BK + ks * 32 + kb];
        #pragma unroll
        for (int n = 0; n < WNr; ++n)
            #pragma unroll
            for (int ks = 0; ks < KSUB; ++ks)
                bf[n][ks] = *(const short8*)
                    &Bs[(wc * WNr * 16 + n * 16 + fr) * BK + ks * 32 + kb];

        #pragma unroll
        for (int ks = 0; ks < KSUB; ++ks)
            #pragma unroll
            for (int m = 0; m < WMr; ++m)
                #pragma unroll
                for (int n = 0; n < WNr; ++n)
                    acc[m][n] = __builtin_amdgcn_mfma_f32_16x16x32_bf16(
                        af[m][ks], bf[n][ks], acc[m][n], 0, 0, 0);
        __syncthreads();
    }

    const int crow = (lane >> 4) * 4;
    const int ccol = lane & 15;

    if (KSPL > 1) {
        float* Cb = (float*)C0v + (size_t)kz * M * N;
        #pragma unroll
        for (int m = 0; m < WMr; ++m) {
            #pragma unroll
            for (int n = 0; n < WNr; ++n) {
                float* cp = Cb + (size_t)(row0 + wr * WMr * 16 + m * 16 + crow) * N
                               + col0 + wc * WNr * 16 + n * 16 + ccol;
                #pragma unroll
                for (int i = 0; i < 4; ++i)
                    cp[(size_t)i * N] = acc[m][n][i];
            }
        }
        return;
    }

    const bool second = SPLIT && (col0 >= split);
    const int ldc = second ? (N - split) : (SPLIT ? split : N);
    const int cb  = second ? (col0 - split) : col0;

    #pragma unroll
    for (int m = 0; m < WMr; ++m) {
        #pragma unroll
        for (int n = 0; n < WNr; ++n) {
            size_t base = (size_t)(row0 + wr * WMr * 16 + m * 16 + crow) * ldc
                          + cb + wc * WNr * 16 + n * 16 + ccol;
            if (second) {
                if (BF1) { ushort_t* cp = (ushort_t*)C1v + base;
                    #pragma unroll
                    for (int i = 0; i < 4; ++i) cp[(size_t)i * ldc] = f2bf(acc[m][n][i]);
                } else { float* cp = (float*)C1v + base;
                    #pragma unroll
                    for (int i = 0; i < 4; ++i) cp[(size_t)i * ldc] = acc[m][n][i];
                }
            } else {
                if (BF0) { ushort_t* cp = (ushort_t*)C0v + base;
                    #pragma unroll
                    for (int i = 0; i < 4; ++i) cp[(size_t)i * ldc] = f2bf(acc[m][n][i]);
                } else { float* cp = (float*)C0v + base;
                    #pragma unroll
                    for (int i = 0; i < 4; ++i) cp[(size_t)i * ldc] = acc[m][n][i];
                }
            }
        }
    }
}

__global__ __launch_bounds__(256)
void out_reduce(const float* __restrict__ part, float* __restrict__ out, int n) {
    int i = (blockIdx.x * 256 + threadIdx.x) * 4;
    if (i + 4 <= n) {
        float4 a = *reinterpret_cast<const float4*>(part + i);
        float4 b = *reinterpret_cast<const float4*>(part + n + i);
        float4 r = {a.x + b.x, a.y + b.y, a.z + b.z, a.w + b.w};
        *reinterpret_cast<float4*>(out + i) = r;
    }
}

// ---------------------------------------------------------------------------
// Merged prep: job A (1024 blocks) x->bf16; job B (4096) W_in^T; job C (2048) W_out^T.
// ---------------------------------------------------------------------------
__device__ __forceinline__ void transp_tile_body(const float* __restrict__ W,
                                                 ushort_t* __restrict__ Wt,
                                                 int R, int C, int bx, int by,
                                                 ushort_t (*tile)[33]) {
    int tx = threadIdx.x & 31, ty = threadIdx.x >> 5;
    int r0 = by * 32, c0 = bx * 32;
    #pragma unroll
    for (int i = 0; i < 32; i += 8)
        tile[ty + i][tx] = f2bf(W[(size_t)(r0 + ty + i) * C + c0 + tx]);
    __syncthreads();
    #pragma unroll
    for (int i = 0; i < 32; i += 8)
        Wt[(size_t)(c0 + ty + i) * R + r0 + tx] = tile[tx][ty + i];
}

__global__ __launch_bounds__(256)
void prep_kernel(const float* __restrict__ x, ushort_t* __restrict__ x_bf,
                 const float* __restrict__ W_in, ushort_t* __restrict__ Wint,
                 const float* __restrict__ W_out, ushort_t* __restrict__ Woutt) {
    __shared__ ushort_t tile[32][33];
    int bid = blockIdx.x;
    if (bid < 1024) {
        int i = (bid * 256 + threadIdx.x) * 8;
        float4 a = *reinterpret_cast<const float4*>(x + i);
        float4 b = *reinterpret_cast<const float4*>(x + i + 4);
        ushort_t o[8] = {f2bf(a.x), f2bf(a.y), f2bf(a.z), f2bf(a.w),
                         f2bf(b.x), f2bf(b.y), f2bf(b.z), f2bf(b.w)};
        *reinterpret_cast<short8*>(x_bf + i) = *reinterpret_cast<short8*>(o);
    } else if (bid < 1024 + 4096) {
        int bi = bid - 1024;
        transp_tile_body(W_in, Wint, 1024, 4096, bi & 127, bi >> 7, tile);
    } else {
        int bi = bid - 5120;
        transp_tile_body(W_out, Woutt, 2048, 1024, bi & 31, bi >> 5, tile);
    }
}

// ---------------------------------------------------------------------------
// Split-K GEMM for x_dbl with FUSED depthwise conv + SiLU (xp in bf16):
// ---------------------------------------------------------------------------
__global__ __launch_bounds__(256)
void gemm_xdbl_convfused(const ushort_t* __restrict__ xp, const float* __restrict__ W,
                         const float* __restrict__ conv_w, const float* __restrict__ conv_b,
                         float* __restrict__ part) {
    __shared__ float Ax[16][68];
    __shared__ float Au[16][65];
    __shared__ float Bs[16][96];

    const int tid = threadIdx.x;
    const int m0 = blockIdx.x * 64;
    const int kbase = blockIdx.y * KS_E;
    const int tx = tid & 15;
    const int ty = tid >> 4;
    const bool bhead = (m0 & (LL - 1)) == 0;

    float acc[4][6] = {};

    for (int k0 = 0; k0 < KS_E; k0 += 16) {
        for (int i = tid; i < 67 * 16; i += 256) {
            int r = i >> 4, k = i & 15;
            float v = 0.f;
            if (!(bhead && r < 3))
                v = bf2f(xp[(size_t)(m0 - 3 + r) * D_INNER + kbase + k0 + k]);
            Ax[k][r] = v;
        }
        #pragma unroll
        for (int j = 0; j < 6; ++j) {
            int idx = j * 256 + tid;
            int row = idx / 96, col = idx - row * 96;
            Bs[row][col] = W[(size_t)(kbase + k0 + row) * 96 + col];
        }
        __syncthreads();
        {
            float4 w4 = *(const float4*)&conv_w[(size_t)(kbase + k0 + tx) * 4];
            float cbv = conv_b[kbase + k0 + tx];
            #pragma unroll
            for (int rr = 0; rr < 4; ++rr) {
                int r = ty + rr * 16;
                float a = cbv;
                a = fmaf(w4.x, Ax[tx][r], a);
                a = fmaf(w4.y, Ax[tx][r + 1], a);
                a = fmaf(w4.z, Ax[tx][r + 2], a);
                a = fmaf(w4.w, Ax[tx][r + 3], a);
                Au[tx][r] = a * sigmoidf_(a);
            }
        }
        __syncthreads();
        #pragma unroll
        for (int kk = 0; kk < 16; ++kk) {
            float a[4], b[6];
            #pragma unroll
            for (int i = 0; i < 4; ++i) a[i] = Au[kk][ty * 4 + i];
            #pragma unroll
            for (int j = 0; j < 6; ++j) b[j] = Bs[kk][tx * 6 + j];
            #pragma unroll
            for (int i = 0; i < 4; ++i)
                #pragma unroll
                for (int j = 0; j < 6; ++j)
                    acc[i][j] = fmaf(a[i], b[j], acc[i][j]);
        }
        __syncthreads();
    }

    float* pblk = part + (size_t)blockIdx.y * BL * 96;
    #pragma unroll
    for (int i = 0; i < 4; ++i)
        #pragma unroll
        for (int j = 0; j < 6; ++j)
            pblk[(size_t)(m0 + ty * 4 + i) * 96 + tx * 6 + j] = acc[i][j];
}

__global__ __launch_bounds__(256)
void xdbl_reduce(const float* __restrict__ part, float* __restrict__ x_dbl) {
    int i = blockIdx.x * 256 + threadIdx.x;
    float s = 0.0f;
    #pragma unroll
    for (int k = 0; k < KSPLIT; ++k)
        s += part[(size_t)k * BL * 96 + i];
    x_dbl[i] = s;
}

// ---------------------------------------------------------------------------
// Delta GEMM: delta(bf16) = softplus(x_dbl[:, :64] @ W_dt + dt_bias).
// ---------------------------------------------------------------------------
__global__ __launch_bounds__(256)
void gemm_delta(const float* __restrict__ A, const float* __restrict__ B,
                ushort_t* __restrict__ C, const float* __restrict__ bias,
                int M, int N, int K, int lda, int ldb, int ldc) {
    __shared__ float As[16][65];
    __shared__ float Bs[16][64];

    const int tid = threadIdx.x;
    const int tx = tid & 15;
    const int ty = tid >> 4;
    const int row0 = blockIdx.y * 64;
    const int col0 = blockIdx.x * 64;

    const int arow = tid >> 4;
    const int acol = tid & 15;
    const int brow = tid >> 6;
    const int bcol = tid & 63;

    float acc[4][4] = {};

    for (int k0 = 0; k0 < K; k0 += 16) {
        #pragma unroll
        for (int p = 0; p < 4; ++p) {
            int r = arow + p * 16;
            As[acol][r] = A[(size_t)(row0 + r) * lda + (k0 + acol)];
        }
        int gc = col0 + bcol;
        #pragma unroll
        for (int p = 0; p < 4; ++p) {
            int r = brow + p * 4;
            Bs[r][bcol] = B[(size_t)(k0 + r) * ldb + gc];
        }
        __syncthreads();
        #pragma unroll
        for (int kk = 0; kk < 16; ++kk) {
            float a[4];
            #pragma unroll
            for (int i = 0; i < 4; ++i) a[i] = As[kk][ty * 4 + i];
            float4 bv = *reinterpret_cast<const float4*>(&Bs[kk][tx * 4]);
            float b4[4] = {bv.x, bv.y, bv.z, bv.w};
            #pragma unroll
            for (int i = 0; i < 4; ++i)
                #pragma unroll
                for (int j = 0; j < 4; ++j)
                    acc[i][j] = fmaf(a[i], b4[j], acc[i][j]);
        }
        __syncthreads();
    }

    #pragma unroll
    for (int i = 0; i < 4; ++i) {
        int gr = row0 + ty * 4 + i;
        #pragma unroll
        for (int j = 0; j < 4; ++j) {
            int gc = col0 + tx * 4 + j;
            float v = acc[i][j] + bias[gc];
            v = (v > 20.0f) ? v : log1pf(__expf(v));
            C[(size_t)gr * ldc + gc] = f2bf(v);
        }
    }
}

// ---------------------------------------------------------------------------
// Chunked selective scan (delta/xp/hend bf16, conv fused, geo fast path).
// g = [b:1][c:6][e:11]. hend layout: [c][b][n][e]. sumdelta: [c][b][e].
// ---------------------------------------------------------------------------
__global__ __launch_bounds__(256)
void scan_phase1(const ushort_t* __restrict__ delta, const ushort_t* __restrict__ xp,
                 const float* __restrict__ conv_w, const float* __restrict__ conv_b,
                 const float* __restrict__ x_dbl, const float* __restrict__ A_log,
                 ushort_t* __restrict__ hend, float* __restrict__ sumdelta) {
    int g = blockIdx.x * 256 + threadIdx.x;
    int e = g & (D_INNER - 1);
    int c = (g >> 11) & (NCHUNK - 1);
    int b = g >> 17;

    float A_en[D_STATE];
    bool geo = true;
    #pragma unroll
    for (int n = 0; n < D_STATE; n += 4) {
        float4 al = *(const float4*)&A_log[e * D_STATE + n];
        A_en[n]     = -__expf(al.x);
        A_en[n + 1] = -__expf(al.y);
        A_en[n + 2] = -__expf(al.z);
        A_en[n + 3] = -__expf(al.w);
    }
    #pragma unroll
    for (int n = 0; n < D_STATE; ++n)
        geo = geo && (fabsf(A_en[n] + (float)(n + 1)) <= 2e-5f * (float)(n + 1));

    const int t0 = c * CHUNK;
    const ushort_t* dptr = delta + (size_t)(b * LL + t0) * D_INNER + e;
    const ushort_t* xptr = xp + (size_t)(b * LL + t0) * D_INNER + e;
    const float* xb   = x_dbl + (size_t)(b * LL + t0) * 96 + DT_RANK;
    float4 w4 = *(const float4*)&conv_w[(size_t)e * 4];
    float cbv = conv_b[e];

    float xw0 = 0.f, xw1 = 0.f, xw2 = 0.f;
    if (c > 0) {
        xw0 = bf2f(xptr[-3 * D_INNER]);
        xw1 = bf2f(xptr[-2 * D_INNER]);
        xw2 = bf2f(xptr[-1 * D_INNER]);
    }

    float h[D_STATE];
    #pragma unroll
    for (int n = 0; n < D_STATE; ++n) h[n] = 0.0f;
    float S = 0.0f;

    if (geo) {
        #pragma unroll 2
        for (int t = 0; t < CHUNK; ++t) {
            float dv = bf2f(dptr[(size_t)t * D_INNER]);
            float x0 = bf2f(xptr[(size_t)t * D_INNER]);
            float a = cbv;
            a = fmaf(w4.x, xw0, a); a = fmaf(w4.y, xw1, a);
            a = fmaf(w4.z, xw2, a); a = fmaf(w4.w, x0, a);
            float uv = a * sigmoidf_(a);
            xw0 = xw1; xw1 = xw2; xw2 = x0;
            const float* xrow = xb + (size_t)t * 96;
            float4 B0 = *(const float4*)(xrow);
            float4 B1 = *(const float4*)(xrow + 4);
            float4 B2 = *(const float4*)(xrow + 8);
            float4 B3 = *(const float4*)(xrow + 12);
            float Bv[16] = {B0.x, B0.y, B0.z, B0.w, B1.x, B1.y, B1.z, B1.w,
                            B2.x, B2.y, B2.z, B2.w, B3.x, B3.y, B3.z, B3.w};
            S += dv;
            float du = dv * uv;
            float q = __expf(-dv);
            float dA = q;
            #pragma unroll
            for (int n = 0; n < D_STATE; ++n) {
                h[n] = fmaf(dA, h[n], du * Bv[n]);
                dA *= q;
            }
        }
    } else {
        for (int t = 0; t < CHUNK; ++t) {
            float dv = bf2f(dptr[(size_t)t * D_INNER]);
            float x0 = bf2f(xptr[(size_t)t * D_INNER]);
            float a = cbv;
            a = fmaf(w4.x, xw0, a); a = fmaf(w4.y, xw1, a);
            a = fmaf(w4.z, xw2, a); a = fmaf(w4.w, x0, a);
            float uv = a * sigmoidf_(a);
            xw0 = xw1; xw1 = xw2; xw2 = x0;
            const float* xrow = xb + (size_t)t * 96;
            float4 B0 = *(const float4*)(xrow);
            float4 B1 = *(const float4*)(xrow + 4);
            float4 B2 = *(const float4*)(xrow + 8);
            float4 B3 = *(const float4*)(xrow + 12);
            float Bv[16] = {B0.x, B0.y, B0.z, B0.w, B1.x, B1.y, B1.z, B1.w,
                            B2.x, B2.y, B2.z, B2.w, B3.x, B3.y, B3.z, B3.w};
            S += dv;
            float du = dv * uv;
            #pragma unroll
            for (int n = 0; n < D_STATE; ++n) {
                float dA = __expf(dv * A_en[n]);
                h[n] = fmaf(dA, h[n], du * Bv[n]);
            }
        }
    }

    size_t rbase = ((size_t)(c * BB + b) * D_STATE) * D_INNER + e;
    #pragma unroll
    for (int n = 0; n < D_STATE; ++n)
        hend[rbase + (size_t)n * D_INNER] = f2bf(h[n]);
    sumdelta[(size_t)(c * BB + b) * D_INNER + e] = S;
}

// In-place: hh holds hend(bf16) on entry, hin(bf16) on exit.
// 4x unrolled: 8 independent loads + 4 exps issue ahead of the 4-fma chain.
__global__ __launch_bounds__(256)
void scan_phase2(const float* __restrict__ A_log, const float* __restrict__ sumdelta,
                 ushort_t* __restrict__ hh) {
    int g = blockIdx.x * 256 + threadIdx.x;
    int e = g & (D_INNER - 1);
    int n = (g >> 11) & (D_STATE - 1);
    int b = g >> 15;
    float A_en = -__expf(A_log[e * D_STATE + n]);
    float np1 = (float)(n + 1);
    if (fabsf(A_en + np1) <= 2e-5f * np1) A_en = -np1;

    const size_t CS = (size_t)BB * D_STATE * D_INNER;   // hh stride per chunk
    const size_t DS = (size_t)BB * D_INNER;             // sumd stride per chunk
    size_t hidx = ((size_t)b * D_STATE + n) * D_INNER + e;
    size_t didx = (size_t)b * D_INNER + e;

    float h = 0.0f;
    #pragma unroll 1
    for (int c = 0; c < NCHUNK; c += 4) {
        float he0 = bf2f(hh[hidx]);
        float he1 = bf2f(hh[hidx + CS]);
        float he2 = bf2f(hh[hidx + 2 * CS]);
        float he3 = bf2f(hh[hidx + 3 * CS]);
        float q0 = __expf(A_en * sumdelta[didx]);
        float q1 = __expf(A_en * sumdelta[didx + DS]);
        float q2 = __expf(A_en * sumdelta[didx + 2 * DS]);
        float q3 = __expf(A_en * sumdelta[didx + 3 * DS]);
        hh[hidx] = f2bf(h);          h = fmaf(q0, h, he0);
        hh[hidx + CS] = f2bf(h);     h = fmaf(q1, h, he1);
        hh[hidx + 2 * CS] = f2bf(h); h = fmaf(q2, h, he2);
        hh[hidx + 3 * CS] = f2bf(h); h = fmaf(q3, h, he3);
        hidx += 4 * CS;
        didx += 4 * DS;
    }
}

__global__ __launch_bounds__(256)
void scan_phase3(const ushort_t* __restrict__ delta, const ushort_t* __restrict__ xp,
                 const float* __restrict__ conv_w, const float* __restrict__ conv_b,
                 const float* __restrict__ x_dbl, const ushort_t* __restrict__ zbf,
                 const float* __restrict__ A_log, const float* __restrict__ D_skip,
                 const ushort_t* __restrict__ hin, ushort_t* __restrict__ ybf) {
    int g = blockIdx.x * 256 + threadIdx.x;
    int e = g & (D_INNER - 1);
    int c = (g >> 11) & (NCHUNK - 1);
    int b = g >> 17;

    float A_en[D_STATE];
    bool geo = true;
    #pragma unroll
    for (int n = 0; n < D_STATE; n += 4) {
        float4 al = *(const float4*)&A_log[e * D_STATE + n];
        A_en[n]     = -__expf(al.x);
        A_en[n + 1] = -__expf(al.y);
        A_en[n + 2] = -__expf(al.z);
        A_en[n + 3] = -__expf(al.w);
    }
    #pragma unroll
    for (int n = 0; n < D_STATE; ++n)
        geo = geo && (fabsf(A_en[n] + (float)(n + 1)) <= 2e-5f * (float)(n + 1));

    float D_e = D_skip[e];
    float h[D_STATE];
    size_t rbase = ((size_t)(c * BB + b) * D_STATE) * D_INNER + e;
    #pragma unroll
    for (int n = 0; n < D_STATE; ++n)
        h[n] = bf2f(hin[rbase + (size_t)n * D_INNER]);

    const int t0 = c * CHUNK;
    const ushort_t* dptr = delta + (size_t)(b * LL + t0) * D_INNER + e;
    const ushort_t* xptr = xp + (size_t)(b * LL + t0) * D_INNER + e;
    const float* xb   = x_dbl + (size_t)(b * LL + t0) * 96 + DT_RANK;
    const ushort_t* zptr = zbf + (size_t)(b * LL + t0) * D_INNER + e;
    ushort_t* yout = ybf + (size_t)(b * LL + t0) * D_INNER + e;
    float4 w4 = *(const float4*)&conv_w[(size_t)e * 4];
    float cbv = conv_b[e];

    float xw0 = 0.f, xw1 = 0.f, xw2 = 0.f;
    if (c > 0) {
        xw0 = bf2f(xptr[-3 * D_INNER]);
        xw1 = bf2f(xptr[-2 * D_INNER]);
        xw2 = bf2f(xptr[-1 * D_INNER]);
    }

    if (geo) {
        #pragma unroll 2
        for (int t = 0; t < CHUNK; ++t) {
            float dv = bf2f(dptr[(size_t)t * D_INNER]);
            float x0 = bf2f(xptr[(size_t)t * D_INNER]);
            float a = cbv;
            a = fmaf(w4.x, xw0, a); a = fmaf(w4.y, xw1, a);
            a = fmaf(w4.z, xw2, a); a = fmaf(w4.w, x0, a);
            float uv = a * sigmoidf_(a);
            xw0 = xw1; xw1 = xw2; xw2 = x0;
            const float* xrow = xb + (size_t)t * 96;
            float4 B0 = *(const float4*)(xrow);
            float4 B1 = *(const float4*)(xrow + 4);
            float4 B2 = *(const float4*)(xrow + 8);
            float4 B3 = *(const float4*)(xrow + 12);
            float4 C0 = *(const float4*)(xrow + 16);
            float4 C1 = *(const float4*)(xrow + 20);
            float4 C2 = *(const float4*)(xrow + 24);
            float4 C3 = *(const float4*)(xrow + 28);
            float Bv[16] = {B0.x, B0.y, B0.z, B0.w, B1.x, B1.y, B1.z, B1.w,
                            B2.x, B2.y, B2.z, B2.w, B3.x, B3.y, B3.z, B3.w};
            float Cv[16] = {C0.x, C0.y, C0.z, C0.w, C1.x, C1.y, C1.z, C1.w,
                            C2.x, C2.y, C2.z, C2.w, C3.x, C3.y, C3.z, C3.w};
            float du = dv * uv;
            float q = __expf(-dv);
            float dA = q;
            float y = 0.0f;
            #pragma unroll
            for (int n = 0; n < D_STATE; ++n) {
                h[n] = fmaf(dA, h[n], du * Bv[n]);
                y = fmaf(h[n], Cv[n], y);
                dA *= q;
            }
            float zv = bf2f(zptr[(size_t)t * D_INNER]);
            float yg = (y + uv * D_e) * (zv * sigmoidf_(zv));
            yout[(size_t)t * D_INNER] = f2bf(yg);
        }
    } else {
        for (int t = 0; t < CHUNK; ++t) {
            float dv = bf2f(dptr[(size_t)t * D_INNER]);
            float x0 = bf2f(xptr[(size_t)t * D_INNER]);
            float a = cbv;
            a = fmaf(w4.x, xw0, a); a = fmaf(w4.y, xw1, a);
            a = fmaf(w4.z, xw2, a); a = fmaf(w4.w, x0, a);
            float uv = a * sigmoidf_(a);
            xw0 = xw1; xw1 = xw2; xw2 = x0;
            const float* xrow = xb + (size_t)t * 96;
            float4 B0 = *(const float4*)(xrow);
            float4 B1 = *(const float4*)(xrow + 4);
            float4 B2 = *(const float4*)(xrow + 8);
            float4 B3 = *(const float4*)(xrow + 12);
            float4 C0 = *(const float4*)(xrow + 16);
            float4 C1 = *(const float4*)(xrow + 20);
            float4 C2 = *(const float4*)(xrow + 24);
            float4 C3 = *(const float4*)(xrow + 28);
            float Bv[16] = {B0.x, B0.y, B0.z, B0.w, B1.x, B1.y, B1.z, B1.w,
                            B2.x, B2.y, B2.z, B2.w, B3.x, B3.y, B3.z, B3.w};
            float Cv[16] = {C0.x, C0.y, C0.z, C0.w, C1.x, C1.y, C1.z, C1.w,
                            C2.x, C2.y, C2.z, C2.w, C3.x, C3.y, C3.z, C3.w};
            float du = dv * uv;
            float y = 0.0f;
            #pragma unroll
            for (int n = 0; n < D_STATE; ++n) {
                float dA = __expf(dv * A_en[n]);
                h[n] = fmaf(dA, h[n], du * Bv[n]);
                y = fmaf(h[n], Cv[n], y);
            }
            float zv = bf2f(zptr[(size_t)t * D_INNER]);
            float yg = (y + uv * D_e) * (zv * sigmoidf_(zv));
            yout[(size_t)t * D_INNER] = f2bf(yg);
        }
    }
}

// ---------------------------------------------------------------------------
extern "C" void kernel_launch(void* const* d_in, const int* in_sizes, int n_in,
                              void* d_out, int out_size, void* d_ws, size_t ws_size,
                              hipStream_t stream) {
    const float* x      = (const float*)d_in[0];
    const float* W_in   = (const float*)d_in[1];
    const float* conv_w = (const float*)d_in[2];
    const float* conv_b = (const float*)d_in[3];
    const float* W_xp   = (const float*)d_in[4];
    const float* W_dt   = (const float*)d_in[5];
    const float* dt_b   = (const float*)d_in[6];
    const float* A_log  = (const float*)d_in[7];
    const float* D_skip = (const float*)d_in[8];
    const float* W_out  = (const float*)d_in[9];
    float* out = (float*)d_out;

    // workspace ledger (float units). Peak = 18M floats = 72 MB (< proven 76.8).
    //   xp_bf  (bf16) [0, 2M)                step1 -> p3
    //   hend   (bf16) [4M, 6M)               p1 -> p3
    //   Wint_bf(bf16) [6M, 8M)               prep -> step1
    //   delta  (bf16) [8M, 9M)               step4 -> p3
    //     xdbl_part   [8M, 11M) (alias f32)  step2 -> step3  (pre-step4, ok)
    //     out_part    [8M, 12M) (alias f32)  step6 -> step7  (delta dead after p3)
    //   z_bf   (bf16) [12M, 14M)             step1 -> p3
    //   x_dbl  (f32)  [14M, +196608)         step3 -> p3
    //   sumd   (f32)  [14M+262144, +262144)  p1 -> p2
    //   ybf    (bf16) [14M+524288, 16M+524288) p3 -> step6
    //     x_bf (bf16) [14M+524288, 15M+524288) (alias) prep -> step1
    //   Woutt  (bf16) [17M, 18M)             prep -> step6
    const size_t M1 = 1024 * 1024;
    float* ws = (float*)d_ws;
    ushort_t* xp_bf = (ushort_t*)ws;
    ushort_t* hend  = (ushort_t*)(ws + 4 * M1);
    ushort_t* Wint_bf = (ushort_t*)(ws + 6 * M1);
    ushort_t* delta = (ushort_t*)(ws + 8 * M1);
    ushort_t* z_bf  = (ushort_t*)(ws + 12 * M1);
    float*    x_dbl = ws + 14 * M1;
    float*    sumd  = ws + 14 * M1 + 262144;
    ushort_t* ybf   = (ushort_t*)(ws + 14 * M1 + 524288);
    float*    xdbl_part = ws + 8 * M1;
    float*    out_part  = ws + 8 * M1;
    ushort_t* x_bf  = ybf;
    ushort_t* Woutt_bf = (ushort_t*)(ws + 17 * M1);

    dim3 blk(256);

    // 0) merged prep: x->bf16, W_in^T, W_out^T
    hipLaunchKernelGGL(prep_kernel, dim3(1024 + 4096 + 2048), blk, 0, stream,
                       x, x_bf, W_in, Wint_bf, W_out, Woutt_bf);
    // 1) [xp(bf16) | z(bf16)] = x @ W_in  (64x128, BK=32, 8x8 supertile swz)
    hipLaunchKernelGGL((gemm_bf16_t<64, 128, 1, 1, 1, 1, 4, 32>),
                       dim3((BL / 64) * (4096 / 128)), blk, 0, stream,
                       x_bf, Wint_bf, (void*)xp_bf, (void*)z_bf,
                       BL, 2 * D_INNER, D_MODEL, D_INNER);
    // 2) x_dbl partials = silu(conv(xp)) @ W_xp   (conv fused, split-K)
    hipLaunchKernelGGL(gemm_xdbl_convfused, dim3(BL / 64, KSPLIT), blk, 0, stream,
                       xp_bf, W_xp, conv_w, conv_b, xdbl_part);
    // 3) reduce partials -> x_dbl
    hipLaunchKernelGGL(xdbl_reduce, dim3((BL * 96) / 256), blk, 0, stream,
                       xdbl_part, x_dbl);
    // 4) delta(bf16) = softplus(x_dbl[:, :64] @ W_dt + dt_bias)
    hipLaunchKernelGGL(gemm_delta, dim3(D_INNER / 64, BL / 64), blk, 0, stream,
                       x_dbl, W_dt, delta, dt_b, BL, D_INNER, DT_RANK, 96, D_INNER, D_INNER);
    // 5) chunked selective scan -> ybf
    hipLaunchKernelGGL(scan_phase1, dim3((BB * NCHUNK * D_INNER) / 256), blk, 0, stream,
                       delta, xp_bf, conv_w, conv_b, x_dbl, A_log, hend, sumd);
    hipLaunchKernelGGL(scan_phase2, dim3((BB * D_STATE * D_INNER) / 256), blk, 0, stream,
                       A_log, sumd, hend);
    hipLaunchKernelGGL(scan_phase3, dim3((BB * NCHUNK * D_INNER) / 256), blk, 0, stream,
                       delta, xp_bf, conv_w, conv_b, x_dbl, z_bf, A_log, D_skip, hend, ybf);
    // 6) out partials = ybf @ W_out  (64x64, BK=32, split-K=2, supertile swz)
    hipLaunchKernelGGL((gemm_bf16_t<64, 64, 0, 0, 0, 2, 8, 32>),
                       dim3((BL / 64) * (D_MODEL / 64) * 2), blk, 0, stream,
                       ybf, Woutt_bf, (void*)out_part, (void*)out_part,
                       BL, D_MODEL, D_INNER, D_MODEL);
    // 7) reduce the two K-halves -> out
    hipLaunchKernelGGL(out_reduce, dim3((BL * D_MODEL) / (256 * 4)), blk, 0, stream,
                       out_part, out, BL * D_MODEL);
}

// Round 19
// 168.770 us; speedup vs baseline: 1.0251x; 1.0032x over previous
//
#include <hip/hip_runtime.h>
#include <math.h>

#define D_MODEL 1024
#define D_INNER 2048
#define D_STATE 16
#define D_CONV  4
#define DT_RANK 64
#define BB      2
#define LL      1024
#define BL      (BB*LL)   // 2048 rows (B*L)
#define CHUNK   16
#define NCHUNK  (LL/CHUNK)   // 64
#define KSPLIT  16           // split-K for x_dbl GEMM
#define KS_E    (D_INNER/KSPLIT)   // 128 e-cols per split

typedef __attribute__((ext_vector_type(8))) short short8;
typedef __attribute__((ext_vector_type(4))) float f32x4;
typedef unsigned short ushort_t;
typedef unsigned int uint_t;

__device__ __forceinline__ float sigmoidf_(float x) { return 1.0f / (1.0f + __expf(-x)); }

__device__ __forceinline__ ushort_t f2bf(float f) {
    uint_t u = __float_as_uint(f);
    uint_t r = (u + 0x7fffu + ((u >> 16) & 1u)) >> 16;
    return (ushort_t)r;
}
__device__ __forceinline__ float bf2f(ushort_t v) {
    return __uint_as_float((uint_t)v << 16);
}

__device__ __forceinline__ void gload_lds16(const void* g, void* l) {
    __builtin_amdgcn_global_load_lds(
        (const __attribute__((address_space(1))) void*)g,
        (__attribute__((address_space(3))) void*)l,
        16, 0, 0);
}

// ---------------------------------------------------------------------------
// bf16 MFMA GEMM, templated tile: C = A[M,K] @ Bt[N,K]^T.
// 4 waves as 2(M) x 2(N); BK=32; 16x16x32 MFMA. 1D grid, XCD-swizzled with
// 8x8-tile SUPERTILE chunking (R18: bounds per-XCD L2 working set ~3 MB).
// SPLIT: col-split epilogue. BF0/BF1: outputs bf16. KSPL>1: split-K partials
// to C0v + kz*M*N (fp32). MINW: blocks/CU target.
// Measured optima: in_proj 64x128 BK=32 MINW=4; out_proj 64x64 BK=32 splitK=2.
// NOTE (R16): cooperative grid.sync scan fusion FAILS under graph capture.
// ---------------------------------------------------------------------------
template<int BM, int BN, int SPLIT, int BF0, int BF1, int KSPL, int MINW, int BK>
__global__ __launch_bounds__(256, MINW)
void gemm_bf16_t(const ushort_t* __restrict__ A, const ushort_t* __restrict__ Bt,
                 void* __restrict__ C0v, void* __restrict__ C1v,
                 int M, int N, int K, int split) {
    constexpr int WMr = BM / 32;
    constexpr int WNr = BN / 32;
    constexpr int KSUB = BK / 32;
    const int nx = N / BN;
    const int ny = M / BM;
    const int per = nx * ny;
    const int nwg = per * KSPL;
    const int wg = ((blockIdx.x & 7) * (nwg >> 3)) + (blockIdx.x >> 3);
    const int kz = (KSPL > 1) ? (wg / per) : 0;
    const int rem = (KSPL > 1) ? (wg % per) : wg;

    int row_t, col_t;
    if ((ny & 7) == 0 && (nx & 7) == 0) {   // 8x8 supertile chunking
        const int chunk = rem >> 6;
        const int within = rem & 63;
        const int ncx = nx >> 3;
        row_t = (chunk / ncx) * 8 + (within >> 3);
        col_t = (chunk % ncx) * 8 + (within & 7);
    } else {
        row_t = rem / nx;
        col_t = rem % nx;
    }
    const int row0 = row_t * BM;
    const int col0 = col_t * BN;
    const int Kh = K / KSPL;
    const int koff = kz * Kh;

    __shared__ __align__(16) ushort_t As[BM * BK];
    __shared__ __align__(16) ushort_t Bs[BN * BK];

    const int tid  = threadIdx.x;
    const int lane = tid & 63;
    const int wave = tid >> 6;
    const int wr = wave >> 1, wc = wave & 1;

    f32x4 acc[WMr][WNr];
    #pragma unroll
    for (int m = 0; m < WMr; ++m)
        #pragma unroll
        for (int n = 0; n < WNr; ++n)
            acc[m][n] = (f32x4){0.f, 0.f, 0.f, 0.f};

    const ushort_t* Ablk = A  + (size_t)row0 * K + koff;
    const ushort_t* Bblk = Bt + (size_t)col0 * K + koff;

    for (int k0 = 0; k0 < Kh; k0 += BK) {
        if (BK == 32) {
            const int r_ld  = tid >> 2;
            const int c8_ld = (tid & 3) * 8;
            #pragma unroll
            for (int i = 0; i < BM / 64; ++i)
                gload_lds16(Ablk + (size_t)(i * 64 + r_ld) * K + k0 + c8_ld,
                            &As[(i * 64 + wave * 16) * 32]);
            #pragma unroll
            for (int i = 0; i < BN / 64; ++i)
                gload_lds16(Bblk + (size_t)(i * 64 + r_ld) * K + k0 + c8_ld,
                            &Bs[(i * 64 + wave * 16) * 32]);
        } else {
            const int r_ld  = tid >> 3;
            const int c8_ld = (tid & 7) * 8;
            #pragma unroll
            for (int i = 0; i < BM / 32; ++i)
                gload_lds16(Ablk + (size_t)(i * 32 + r_ld) * K + k0 + c8_ld,
                            &As[(i * 32 + wave * 8) * 64]);
            #pragma unroll
            for (int i = 0; i < BN / 32; ++i)
                gload_lds16(Bblk + (size_t)(i * 32 + r_ld) * K + k0 + c8_ld,
                            &Bs[(i * 32 + wave * 8) * 64]);
        }
        __syncthreads();

        short8 af[WMr][KSUB], bf[WNr][KSUB];
        const int fr = lane & 15;
        const int kb = (lane >> 4) * 8;
        #pragma unroll
        for (int m = 0; m < WMr; ++m)
            #pragma unroll
            for (int ks = 0; ks < KSUB; ++ks)
                af[m][ks] = *(const short8*)
                    &As[(wr * WMr * 16 + m * 16 + fr) * BK + ks * 32 + kb];
        #pragma unroll
        for (int n = 0; n < WNr; ++n)
            #pragma unroll
            for (int ks = 0; ks < KSUB; ++ks)
                bf[n][ks] = *(const short8*)
                    &Bs[(wc * WNr * 16 + n * 16 + fr) * BK + ks * 32 + kb];

        #pragma unroll
        for (int ks = 0; ks < KSUB; ++ks)
            #pragma unroll
            for (int m = 0; m < WMr; ++m)
                #pragma unroll
                for (int n = 0; n < WNr; ++n)
                    acc[m][n] = __builtin_amdgcn_mfma_f32_16x16x32_bf16(
                        af[m][ks], bf[n][ks], acc[m][n], 0, 0, 0);
        __syncthreads();
    }

    const int crow = (lane >> 4) * 4;
    const int ccol = lane & 15;

    if (KSPL > 1) {
        float* Cb = (float*)C0v + (size_t)kz * M * N;
        #pragma unroll
        for (int m = 0; m < WMr; ++m) {
            #pragma unroll
            for (int n = 0; n < WNr; ++n) {
                float* cp = Cb + (size_t)(row0 + wr * WMr * 16 + m * 16 + crow) * N
                               + col0 + wc * WNr * 16 + n * 16 + ccol;
                #pragma unroll
                for (int i = 0; i < 4; ++i)
                    cp[(size_t)i * N] = acc[m][n][i];
            }
        }
        return;
    }

    const bool second = SPLIT && (col0 >= split);
    const int ldc = second ? (N - split) : (SPLIT ? split : N);
    const int cb  = second ? (col0 - split) : col0;

    #pragma unroll
    for (int m = 0; m < WMr; ++m) {
        #pragma unroll
        for (int n = 0; n < WNr; ++n) {
            size_t base = (size_t)(row0 + wr * WMr * 16 + m * 16 + crow) * ldc
                          + cb + wc * WNr * 16 + n * 16 + ccol;
            if (second) {
                if (BF1) { ushort_t* cp = (ushort_t*)C1v + base;
                    #pragma unroll
                    for (int i = 0; i < 4; ++i) cp[(size_t)i * ldc] = f2bf(acc[m][n][i]);
                } else { float* cp = (float*)C1v + base;
                    #pragma unroll
                    for (int i = 0; i < 4; ++i) cp[(size_t)i * ldc] = acc[m][n][i];
                }
            } else {
                if (BF0) { ushort_t* cp = (ushort_t*)C0v + base;
                    #pragma unroll
                    for (int i = 0; i < 4; ++i) cp[(size_t)i * ldc] = f2bf(acc[m][n][i]);
                } else { float* cp = (float*)C0v + base;
                    #pragma unroll
                    for (int i = 0; i < 4; ++i) cp[(size_t)i * ldc] = acc[m][n][i];
                }
            }
        }
    }
}

__global__ __launch_bounds__(256)
void out_reduce(const float* __restrict__ part, float* __restrict__ out, int n) {
    int i = (blockIdx.x * 256 + threadIdx.x) * 4;
    if (i + 4 <= n) {
        float4 a = *reinterpret_cast<const float4*>(part + i);
        float4 b = *reinterpret_cast<const float4*>(part + n + i);
        float4 r = {a.x + b.x, a.y + b.y, a.z + b.z, a.w + b.w};
        *reinterpret_cast<float4*>(out + i) = r;
    }
}

// ---------------------------------------------------------------------------
// Merged prep: job A (1024 blocks) x->bf16; job B (4096) W_in^T; job C (2048) W_out^T.
// ---------------------------------------------------------------------------
__device__ __forceinline__ void transp_tile_body(const float* __restrict__ W,
                                                 ushort_t* __restrict__ Wt,
                                                 int R, int C, int bx, int by,
                                                 ushort_t (*tile)[33]) {
    int tx = threadIdx.x & 31, ty = threadIdx.x >> 5;
    int r0 = by * 32, c0 = bx * 32;
    #pragma unroll
    for (int i = 0; i < 32; i += 8)
        tile[ty + i][tx] = f2bf(W[(size_t)(r0 + ty + i) * C + c0 + tx]);
    __syncthreads();
    #pragma unroll
    for (int i = 0; i < 32; i += 8)
        Wt[(size_t)(c0 + ty + i) * R + r0 + tx] = tile[tx][ty + i];
}

__global__ __launch_bounds__(256)
void prep_kernel(const float* __restrict__ x, ushort_t* __restrict__ x_bf,
                 const float* __restrict__ W_in, ushort_t* __restrict__ Wint,
                 const float* __restrict__ W_out, ushort_t* __restrict__ Woutt) {
    __shared__ ushort_t tile[32][33];
    int bid = blockIdx.x;
    if (bid < 1024) {
        int i = (bid * 256 + threadIdx.x) * 8;
        float4 a = *reinterpret_cast<const float4*>(x + i);
        float4 b = *reinterpret_cast<const float4*>(x + i + 4);
        ushort_t o[8] = {f2bf(a.x), f2bf(a.y), f2bf(a.z), f2bf(a.w),
                         f2bf(b.x), f2bf(b.y), f2bf(b.z), f2bf(b.w)};
        *reinterpret_cast<short8*>(x_bf + i) = *reinterpret_cast<short8*>(o);
    } else if (bid < 1024 + 4096) {
        int bi = bid - 1024;
        transp_tile_body(W_in, Wint, 1024, 4096, bi & 127, bi >> 7, tile);
    } else {
        int bi = bid - 5120;
        transp_tile_body(W_out, Woutt, 2048, 1024, bi & 31, bi >> 5, tile);
    }
}

// ---------------------------------------------------------------------------
// Split-K GEMM for x_dbl with FUSED depthwise conv + SiLU (xp in bf16):
// ---------------------------------------------------------------------------
__global__ __launch_bounds__(256)
void gemm_xdbl_convfused(const ushort_t* __restrict__ xp, const float* __restrict__ W,
                         const float* __restrict__ conv_w, const float* __restrict__ conv_b,
                         float* __restrict__ part) {
    __shared__ float Ax[16][68];
    __shared__ float Au[16][65];
    __shared__ float Bs[16][96];

    const int tid = threadIdx.x;
    const int m0 = blockIdx.x * 64;
    const int kbase = blockIdx.y * KS_E;
    const int tx = tid & 15;
    const int ty = tid >> 4;
    const bool bhead = (m0 & (LL - 1)) == 0;

    float acc[4][6] = {};

    for (int k0 = 0; k0 < KS_E; k0 += 16) {
        for (int i = tid; i < 67 * 16; i += 256) {
            int r = i >> 4, k = i & 15;
            float v = 0.f;
            if (!(bhead && r < 3))
                v = bf2f(xp[(size_t)(m0 - 3 + r) * D_INNER + kbase + k0 + k]);
            Ax[k][r] = v;
        }
        #pragma unroll
        for (int j = 0; j < 6; ++j) {
            int idx = j * 256 + tid;
            int row = idx / 96, col = idx - row * 96;
            Bs[row][col] = W[(size_t)(kbase + k0 + row) * 96 + col];
        }
        __syncthreads();
        {
            float4 w4 = *(const float4*)&conv_w[(size_t)(kbase + k0 + tx) * 4];
            float cbv = conv_b[kbase + k0 + tx];
            #pragma unroll
            for (int rr = 0; rr < 4; ++rr) {
                int r = ty + rr * 16;
                float a = cbv;
                a = fmaf(w4.x, Ax[tx][r], a);
                a = fmaf(w4.y, Ax[tx][r + 1], a);
                a = fmaf(w4.z, Ax[tx][r + 2], a);
                a = fmaf(w4.w, Ax[tx][r + 3], a);
                Au[tx][r] = a * sigmoidf_(a);
            }
        }
        __syncthreads();
        #pragma unroll
        for (int kk = 0; kk < 16; ++kk) {
            float a[4], b[6];
            #pragma unroll
            for (int i = 0; i < 4; ++i) a[i] = Au[kk][ty * 4 + i];
            #pragma unroll
            for (int j = 0; j < 6; ++j) b[j] = Bs[kk][tx * 6 + j];
            #pragma unroll
            for (int i = 0; i < 4; ++i)
                #pragma unroll
                for (int j = 0; j < 6; ++j)
                    acc[i][j] = fmaf(a[i], b[j], acc[i][j]);
        }
        __syncthreads();
    }

    float* pblk = part + (size_t)blockIdx.y * BL * 96;
    #pragma unroll
    for (int i = 0; i < 4; ++i)
        #pragma unroll
        for (int j = 0; j < 6; ++j)
            pblk[(size_t)(m0 + ty * 4 + i) * 96 + tx * 6 + j] = acc[i][j];
}

__global__ __launch_bounds__(256)
void xdbl_reduce(const float* __restrict__ part, float* __restrict__ x_dbl) {
    int i = blockIdx.x * 256 + threadIdx.x;
    float s = 0.0f;
    #pragma unroll
    for (int k = 0; k < KSPLIT; ++k)
        s += part[(size_t)k * BL * 96 + i];
    x_dbl[i] = s;
}

// ---------------------------------------------------------------------------
// Delta GEMM: delta(bf16) = softplus(x_dbl[:, :64] @ W_dt + dt_bias).
// ---------------------------------------------------------------------------
__global__ __launch_bounds__(256)
void gemm_delta(const float* __restrict__ A, const float* __restrict__ B,
                ushort_t* __restrict__ C, const float* __restrict__ bias,
                int M, int N, int K, int lda, int ldb, int ldc) {
    __shared__ float As[16][65];
    __shared__ float Bs[16][64];

    const int tid = threadIdx.x;
    const int tx = tid & 15;
    const int ty = tid >> 4;
    const int row0 = blockIdx.y * 64;
    const int col0 = blockIdx.x * 64;

    const int arow = tid >> 4;
    const int acol = tid & 15;
    const int brow = tid >> 6;
    const int bcol = tid & 63;

    float acc[4][4] = {};

    for (int k0 = 0; k0 < K; k0 += 16) {
        #pragma unroll
        for (int p = 0; p < 4; ++p) {
            int r = arow + p * 16;
            As[acol][r] = A[(size_t)(row0 + r) * lda + (k0 + acol)];
        }
        int gc = col0 + bcol;
        #pragma unroll
        for (int p = 0; p < 4; ++p) {
            int r = brow + p * 4;
            Bs[r][bcol] = B[(size_t)(k0 + r) * ldb + gc];
        }
        __syncthreads();
        #pragma unroll
        for (int kk = 0; kk < 16; ++kk) {
            float a[4];
            #pragma unroll
            for (int i = 0; i < 4; ++i) a[i] = As[kk][ty * 4 + i];
            float4 bv = *reinterpret_cast<const float4*>(&Bs[kk][tx * 4]);
            float b4[4] = {bv.x, bv.y, bv.z, bv.w};
            #pragma unroll
            for (int i = 0; i < 4; ++i)
                #pragma unroll
                for (int j = 0; j < 4; ++j)
                    acc[i][j] = fmaf(a[i], b4[j], acc[i][j]);
        }
        __syncthreads();
    }

    #pragma unroll
    for (int i = 0; i < 4; ++i) {
        int gr = row0 + ty * 4 + i;
        #pragma unroll
        for (int j = 0; j < 4; ++j) {
            int gc = col0 + tx * 4 + j;
            float v = acc[i][j] + bias[gc];
            v = (v > 20.0f) ? v : log1pf(__expf(v));
            C[(size_t)gr * ldc + gc] = f2bf(v);
        }
    }
}

// ---------------------------------------------------------------------------
// Chunked selective scan (delta/xp/hend bf16, conv fused, geo fast path).
// g = [b:1][c:6][e:11]. hend layout: [c][b][n][e]. sumdelta: [c][b][e].
// R19: unroll 4 on geo t-loops (latency-bound gather loops; wider load
// window, per-iteration fma order unchanged -> bit-identical).
// ---------------------------------------------------------------------------
__global__ __launch_bounds__(256)
void scan_phase1(const ushort_t* __restrict__ delta, const ushort_t* __restrict__ xp,
                 const float* __restrict__ conv_w, const float* __restrict__ conv_b,
                 const float* __restrict__ x_dbl, const float* __restrict__ A_log,
                 ushort_t* __restrict__ hend, float* __restrict__ sumdelta) {
    int g = blockIdx.x * 256 + threadIdx.x;
    int e = g & (D_INNER - 1);
    int c = (g >> 11) & (NCHUNK - 1);
    int b = g >> 17;

    float A_en[D_STATE];
    bool geo = true;
    #pragma unroll
    for (int n = 0; n < D_STATE; n += 4) {
        float4 al = *(const float4*)&A_log[e * D_STATE + n];
        A_en[n]     = -__expf(al.x);
        A_en[n + 1] = -__expf(al.y);
        A_en[n + 2] = -__expf(al.z);
        A_en[n + 3] = -__expf(al.w);
    }
    #pragma unroll
    for (int n = 0; n < D_STATE; ++n)
        geo = geo && (fabsf(A_en[n] + (float)(n + 1)) <= 2e-5f * (float)(n + 1));

    const int t0 = c * CHUNK;
    const ushort_t* dptr = delta + (size_t)(b * LL + t0) * D_INNER + e;
    const ushort_t* xptr = xp + (size_t)(b * LL + t0) * D_INNER + e;
    const float* xb   = x_dbl + (size_t)(b * LL + t0) * 96 + DT_RANK;
    float4 w4 = *(const float4*)&conv_w[(size_t)e * 4];
    float cbv = conv_b[e];

    float xw0 = 0.f, xw1 = 0.f, xw2 = 0.f;
    if (c > 0) {
        xw0 = bf2f(xptr[-3 * D_INNER]);
        xw1 = bf2f(xptr[-2 * D_INNER]);
        xw2 = bf2f(xptr[-1 * D_INNER]);
    }

    float h[D_STATE];
    #pragma unroll
    for (int n = 0; n < D_STATE; ++n) h[n] = 0.0f;
    float S = 0.0f;

    if (geo) {
        #pragma unroll 4
        for (int t = 0; t < CHUNK; ++t) {
            float dv = bf2f(dptr[(size_t)t * D_INNER]);
            float x0 = bf2f(xptr[(size_t)t * D_INNER]);
            float a = cbv;
            a = fmaf(w4.x, xw0, a); a = fmaf(w4.y, xw1, a);
            a = fmaf(w4.z, xw2, a); a = fmaf(w4.w, x0, a);
            float uv = a * sigmoidf_(a);
            xw0 = xw1; xw1 = xw2; xw2 = x0;
            const float* xrow = xb + (size_t)t * 96;
            float4 B0 = *(const float4*)(xrow);
            float4 B1 = *(const float4*)(xrow + 4);
            float4 B2 = *(const float4*)(xrow + 8);
            float4 B3 = *(const float4*)(xrow + 12);
            float Bv[16] = {B0.x, B0.y, B0.z, B0.w, B1.x, B1.y, B1.z, B1.w,
                            B2.x, B2.y, B2.z, B2.w, B3.x, B3.y, B3.z, B3.w};
            S += dv;
            float du = dv * uv;
            float q = __expf(-dv);
            float dA = q;
            #pragma unroll
            for (int n = 0; n < D_STATE; ++n) {
                h[n] = fmaf(dA, h[n], du * Bv[n]);
                dA *= q;
            }
        }
    } else {
        for (int t = 0; t < CHUNK; ++t) {
            float dv = bf2f(dptr[(size_t)t * D_INNER]);
            float x0 = bf2f(xptr[(size_t)t * D_INNER]);
            float a = cbv;
            a = fmaf(w4.x, xw0, a); a = fmaf(w4.y, xw1, a);
            a = fmaf(w4.z, xw2, a); a = fmaf(w4.w, x0, a);
            float uv = a * sigmoidf_(a);
            xw0 = xw1; xw1 = xw2; xw2 = x0;
            const float* xrow = xb + (size_t)t * 96;
            float4 B0 = *(const float4*)(xrow);
            float4 B1 = *(const float4*)(xrow + 4);
            float4 B2 = *(const float4*)(xrow + 8);
            float4 B3 = *(const float4*)(xrow + 12);
            float Bv[16] = {B0.x, B0.y, B0.z, B0.w, B1.x, B1.y, B1.z, B1.w,
                            B2.x, B2.y, B2.z, B2.w, B3.x, B3.y, B3.z, B3.w};
            S += dv;
            float du = dv * uv;
            #pragma unroll
            for (int n = 0; n < D_STATE; ++n) {
                float dA = __expf(dv * A_en[n]);
                h[n] = fmaf(dA, h[n], du * Bv[n]);
            }
        }
    }

    size_t rbase = ((size_t)(c * BB + b) * D_STATE) * D_INNER + e;
    #pragma unroll
    for (int n = 0; n < D_STATE; ++n)
        hend[rbase + (size_t)n * D_INNER] = f2bf(h[n]);
    sumdelta[(size_t)(c * BB + b) * D_INNER + e] = S;
}

// In-place: hh holds hend(bf16) on entry, hin(bf16) on exit.
// 8x unrolled: 16 independent loads + 8 exps issue ahead of the fma chain.
__global__ __launch_bounds__(256)
void scan_phase2(const float* __restrict__ A_log, const float* __restrict__ sumdelta,
                 ushort_t* __restrict__ hh) {
    int g = blockIdx.x * 256 + threadIdx.x;
    int e = g & (D_INNER - 1);
    int n = (g >> 11) & (D_STATE - 1);
    int b = g >> 15;
    float A_en = -__expf(A_log[e * D_STATE + n]);
    float np1 = (float)(n + 1);
    if (fabsf(A_en + np1) <= 2e-5f * np1) A_en = -np1;

    const size_t CS = (size_t)BB * D_STATE * D_INNER;   // hh stride per chunk
    const size_t DS = (size_t)BB * D_INNER;             // sumd stride per chunk
    size_t hidx = ((size_t)b * D_STATE + n) * D_INNER + e;
    size_t didx = (size_t)b * D_INNER + e;

    float h = 0.0f;
    #pragma unroll 1
    for (int c = 0; c < NCHUNK; c += 8) {
        float he[8], q[8];
        #pragma unroll
        for (int j = 0; j < 8; ++j) {
            he[j] = bf2f(hh[hidx + (size_t)j * CS]);
            q[j]  = __expf(A_en * sumdelta[didx + (size_t)j * DS]);
        }
        #pragma unroll
        for (int j = 0; j < 8; ++j) {
            hh[hidx + (size_t)j * CS] = f2bf(h);
            h = fmaf(q[j], h, he[j]);
        }
        hidx += 8 * CS;
        didx += 8 * DS;
    }
}

__global__ __launch_bounds__(256)
void scan_phase3(const ushort_t* __restrict__ delta, const ushort_t* __restrict__ xp,
                 const float* __restrict__ conv_w, const float* __restrict__ conv_b,
                 const float* __restrict__ x_dbl, const ushort_t* __restrict__ zbf,
                 const float* __restrict__ A_log, const float* __restrict__ D_skip,
                 const ushort_t* __restrict__ hin, ushort_t* __restrict__ ybf) {
    int g = blockIdx.x * 256 + threadIdx.x;
    int e = g & (D_INNER - 1);
    int c = (g >> 11) & (NCHUNK - 1);
    int b = g >> 17;

    float A_en[D_STATE];
    bool geo = true;
    #pragma unroll
    for (int n = 0; n < D_STATE; n += 4) {
        float4 al = *(const float4*)&A_log[e * D_STATE + n];
        A_en[n]     = -__expf(al.x);
        A_en[n + 1] = -__expf(al.y);
        A_en[n + 2] = -__expf(al.z);
        A_en[n + 3] = -__expf(al.w);
    }
    #pragma unroll
    for (int n = 0; n < D_STATE; ++n)
        geo = geo && (fabsf(A_en[n] + (float)(n + 1)) <= 2e-5f * (float)(n + 1));

    float D_e = D_skip[e];
    float h[D_STATE];
    size_t rbase = ((size_t)(c * BB + b) * D_STATE) * D_INNER + e;
    #pragma unroll
    for (int n = 0; n < D_STATE; ++n)
        h[n] = bf2f(hin[rbase + (size_t)n * D_INNER]);

    const int t0 = c * CHUNK;
    const ushort_t* dptr = delta + (size_t)(b * LL + t0) * D_INNER + e;
    const ushort_t* xptr = xp + (size_t)(b * LL + t0) * D_INNER + e;
    const float* xb   = x_dbl + (size_t)(b * LL + t0) * 96 + DT_RANK;
    const ushort_t* zptr = zbf + (size_t)(b * LL + t0) * D_INNER + e;
    ushort_t* yout = ybf + (size_t)(b * LL + t0) * D_INNER + e;
    float4 w4 = *(const float4*)&conv_w[(size_t)e * 4];
    float cbv = conv_b[e];

    float xw0 = 0.f, xw1 = 0.f, xw2 = 0.f;
    if (c > 0) {
        xw0 = bf2f(xptr[-3 * D_INNER]);
        xw1 = bf2f(xptr[-2 * D_INNER]);
        xw2 = bf2f(xptr[-1 * D_INNER]);
    }

    if (geo) {
        #pragma unroll 4
        for (int t = 0; t < CHUNK; ++t) {
            float dv = bf2f(dptr[(size_t)t * D_INNER]);
            float x0 = bf2f(xptr[(size_t)t * D_INNER]);
            float a = cbv;
            a = fmaf(w4.x, xw0, a); a = fmaf(w4.y, xw1, a);
            a = fmaf(w4.z, xw2, a); a = fmaf(w4.w, x0, a);
            float uv = a * sigmoidf_(a);
            xw0 = xw1; xw1 = xw2; xw2 = x0;
            const float* xrow = xb + (size_t)t * 96;
            float4 B0 = *(const float4*)(xrow);
            float4 B1 = *(const float4*)(xrow + 4);
            float4 B2 = *(const float4*)(xrow + 8);
            float4 B3 = *(const float4*)(xrow + 12);
            float4 C0 = *(const float4*)(xrow + 16);
            float4 C1 = *(const float4*)(xrow + 20);
            float4 C2 = *(const float4*)(xrow + 24);
            float4 C3 = *(const float4*)(xrow + 28);
            float Bv[16] = {B0.x, B0.y, B0.z, B0.w, B1.x, B1.y, B1.z, B1.w,
                            B2.x, B2.y, B2.z, B2.w, B3.x, B3.y, B3.z, B3.w};
            float Cv[16] = {C0.x, C0.y, C0.z, C0.w, C1.x, C1.y, C1.z, C1.w,
                            C2.x, C2.y, C2.z, C2.w, C3.x, C3.y, C3.z, C3.w};
            float du = dv * uv;
            float q = __expf(-dv);
            float dA = q;
            float y = 0.0f;
            #pragma unroll
            for (int n = 0; n < D_STATE; ++n) {
                h[n] = fmaf(dA, h[n], du * Bv[n]);
                y = fmaf(h[n], Cv[n], y);
                dA *= q;
            }
            float zv = bf2f(zptr[(size_t)t * D_INNER]);
            float yg = (y + uv * D_e) * (zv * sigmoidf_(zv));
            yout[(size_t)t * D_INNER] = f2bf(yg);
        }
    } else {
        for (int t = 0; t < CHUNK; ++t) {
            float dv = bf2f(dptr[(size_t)t * D_INNER]);
            float x0 = bf2f(xptr[(size_t)t * D_INNER]);
            float a = cbv;
            a = fmaf(w4.x, xw0, a); a = fmaf(w4.y, xw1, a);
            a = fmaf(w4.z, xw2, a); a = fmaf(w4.w, x0, a);
            float uv = a * sigmoidf_(a);
            xw0 = xw1; xw1 = xw2; xw2 = x0;
            const float* xrow = xb + (size_t)t * 96;
            float4 B0 = *(const float4*)(xrow);
            float4 B1 = *(const float4*)(xrow + 4);
            float4 B2 = *(const float4*)(xrow + 8);
            float4 B3 = *(const float4*)(xrow + 12);
            float4 C0 = *(const float4*)(xrow + 16);
            float4 C1 = *(const float4*)(xrow + 20);
            float4 C2 = *(const float4*)(xrow + 24);
            float4 C3 = *(const float4*)(xrow + 28);
            float Bv[16] = {B0.x, B0.y, B0.z, B0.w, B1.x, B1.y, B1.z, B1.w,
                            B2.x, B2.y, B2.z, B2.w, B3.x, B3.y, B3.z, B3.w};
            float Cv[16] = {C0.x, C0.y, C0.z, C0.w, C1.x, C1.y, C1.z, C1.w,
                            C2.x, C2.y, C2.z, C2.w, C3.x, C3.y, C3.z, C3.w};
            float du = dv * uv;
            float y = 0.0f;
            #pragma unroll
            for (int n = 0; n < D_STATE; ++n) {
                float dA = __expf(dv * A_en[n]);
                h[n] = fmaf(dA, h[n], du * Bv[n]);
                y = fmaf(h[n], Cv[n], y);
            }
            float zv = bf2f(zptr[(size_t)t * D_INNER]);
            float yg = (y + uv * D_e) * (zv * sigmoidf_(zv));
            yout[(size_t)t * D_INNER] = f2bf(yg);
        }
    }
}

// ---------------------------------------------------------------------------
extern "C" void kernel_launch(void* const* d_in, const int* in_sizes, int n_in,
                              void* d_out, int out_size, void* d_ws, size_t ws_size,
                              hipStream_t stream) {
    const float* x      = (const float*)d_in[0];
    const float* W_in   = (const float*)d_in[1];
    const float* conv_w = (const float*)d_in[2];
    const float* conv_b = (const float*)d_in[3];
    const float* W_xp   = (const float*)d_in[4];
    const float* W_dt   = (const float*)d_in[5];
    const float* dt_b   = (const float*)d_in[6];
    const float* A_log  = (const float*)d_in[7];
    const float* D_skip = (const float*)d_in[8];
    const float* W_out  = (const float*)d_in[9];
    float* out = (float*)d_out;

    // workspace ledger (float units). Peak = 18M floats = 72 MB (< proven 76.8).
    //   xp_bf  (bf16) [0, 2M)                step1 -> p3
    //   hend   (bf16) [4M, 6M)               p1 -> p3
    //   Wint_bf(bf16) [6M, 8M)               prep -> step1
    //   delta  (bf16) [8M, 9M)               step4 -> p3
    //     xdbl_part   [8M, 11M) (alias f32)  step2 -> step3  (pre-step4, ok)
    //     out_part    [8M, 12M) (alias f32)  step6 -> step7  (delta dead after p3)
    //   z_bf   (bf16) [12M, 14M)             step1 -> p3
    //   x_dbl  (f32)  [14M, +196608)         step3 -> p3
    //   sumd   (f32)  [14M+262144, +262144)  p1 -> p2
    //   ybf    (bf16) [14M+524288, 16M+524288) p3 -> step6
    //     x_bf (bf16) [14M+524288, 15M+524288) (alias) prep -> step1
    //   Woutt  (bf16) [17M, 18M)             prep -> step6
    const size_t M1 = 1024 * 1024;
    float* ws = (float*)d_ws;
    ushort_t* xp_bf = (ushort_t*)ws;
    ushort_t* hend  = (ushort_t*)(ws + 4 * M1);
    ushort_t* Wint_bf = (ushort_t*)(ws + 6 * M1);
    ushort_t* delta = (ushort_t*)(ws + 8 * M1);
    ushort_t* z_bf  = (ushort_t*)(ws + 12 * M1);
    float*    x_dbl = ws + 14 * M1;
    float*    sumd  = ws + 14 * M1 + 262144;
    ushort_t* ybf   = (ushort_t*)(ws + 14 * M1 + 524288);
    float*    xdbl_part = ws + 8 * M1;
    float*    out_part  = ws + 8 * M1;
    ushort_t* x_bf  = ybf;
    ushort_t* Woutt_bf = (ushort_t*)(ws + 17 * M1);

    dim3 blk(256);

    // 0) merged prep: x->bf16, W_in^T, W_out^T
    hipLaunchKernelGGL(prep_kernel, dim3(1024 + 4096 + 2048), blk, 0, stream,
                       x, x_bf, W_in, Wint_bf, W_out, Woutt_bf);
    // 1) [xp(bf16) | z(bf16)] = x @ W_in  (64x128, BK=32, 8x8 supertile swz)
    hipLaunchKernelGGL((gemm_bf16_t<64, 128, 1, 1, 1, 1, 4, 32>),
                       dim3((BL / 64) * (4096 / 128)), blk, 0, stream,
                       x_bf, Wint_bf, (void*)xp_bf, (void*)z_bf,
                       BL, 2 * D_INNER, D_MODEL, D_INNER);
    // 2) x_dbl partials = silu(conv(xp)) @ W_xp   (conv fused, split-K)
    hipLaunchKernelGGL(gemm_xdbl_convfused, dim3(BL / 64, KSPLIT), blk, 0, stream,
                       xp_bf, W_xp, conv_w, conv_b, xdbl_part);
    // 3) reduce partials -> x_dbl
    hipLaunchKernelGGL(xdbl_reduce, dim3((BL * 96) / 256), blk, 0, stream,
                       xdbl_part, x_dbl);
    // 4) delta(bf16) = softplus(x_dbl[:, :64] @ W_dt + dt_bias)
    hipLaunchKernelGGL(gemm_delta, dim3(D_INNER / 64, BL / 64), blk, 0, stream,
                       x_dbl, W_dt, delta, dt_b, BL, D_INNER, DT_RANK, 96, D_INNER, D_INNER);
    // 5) chunked selective scan -> ybf
    hipLaunchKernelGGL(scan_phase1, dim3((BB * NCHUNK * D_INNER) / 256), blk, 0, stream,
                       delta, xp_bf, conv_w, conv_b, x_dbl, A_log, hend, sumd);
    hipLaunchKernelGGL(scan_phase2, dim3((BB * D_STATE * D_INNER) / 256), blk, 0, stream,
                       A_log, sumd, hend);
    hipLaunchKernelGGL(scan_phase3, dim3((BB * NCHUNK * D_INNER) / 256), blk, 0, stream,
                       delta, xp_bf, conv_w, conv_b, x_dbl, z_bf, A_log, D_skip, hend, ybf);
    // 6) out partials = ybf @ W_out  (64x64, BK=32, split-K=2, supertile swz)
    hipLaunchKernelGGL((gemm_bf16_t<64, 64, 0, 0, 0, 2, 8, 32>),
                       dim3((BL / 64) * (D_MODEL / 64) * 2), blk, 0, stream,
                       ybf, Woutt_bf, (void*)out_part, (void*)out_part,
                       BL, D_MODEL, D_INNER, D_MODEL);
    // 7) reduce the two K-halves -> out
    hipLaunchKernelGGL(out_reduce, dim3((BL * D_MODEL) / (256 * 4)), blk, 0, stream,
                       out_part, out, BL * D_MODEL);
}